// Round 17
// baseline (312.714 us; speedup 1.0000x reference)
//
#include <hip/hip_runtime.h>

// MoE transformer block: prep(sincos+weight transposes+LN1) -> QKV(+RoPE) ->
// split-KV causal flash attn -> proj+res -> LN2+router -> assign -> expert
// FFN (bf16 split-K partials) -> combine.
// Transposed weights stored K-BLOCKED [K/64][N][64]. Prep tiles are now
// 64k x 256n: 1KB-contiguous reads AND 4KB-contiguous writes.
// GEMMs: bf16 MFMA 32x32x16, 128^2 tile, BK=64, global_load_lds dwordx4,
// T2 XOR-swizzle, 2-phase double-buffered pipeline with counted vmcnt.

#define TB 1024   // T
#define DD 1024   // D
#define NTOK 2048 // B*T
#define NEXPERT 8
#define CAPN 512
#define DFF 4096

typedef __attribute__((ext_vector_type(4))) float f32x4;
typedef __attribute__((ext_vector_type(16))) float f32x16;
typedef __attribute__((ext_vector_type(8))) short short8;
typedef __attribute__((ext_vector_type(4))) short short4v;
typedef unsigned short u16;
typedef unsigned int u32;

__device__ __forceinline__ u16 f2bf(float f){
  union { float f; u32 u; } v; v.f = f;
  u32 u = v.u;
  u32 r = (u + 0x7fffu + ((u >> 16) & 1u)) >> 16;
  return (u16)r;
}
__device__ __forceinline__ float bf2f(u16 b){
  union { u32 u; float f; } v; v.u = ((u32)b) << 16;
  return v.f;
}
__device__ __forceinline__ float waveRedSum(float v){
#pragma unroll
  for (int o = 1; o < 64; o <<= 1) v += __shfl_xor(v, o);
  return v;
}

// async global->LDS, 16B per lane, wave-uniform LDS base + lane*16
__device__ __forceinline__ void gl16(const u16* g, u16* l){
  __builtin_amdgcn_global_load_lds(
    (const __attribute__((address_space(1))) u32*)g,
    (__attribute__((address_space(3))) u32*)l, 16, 0, 0);
}

// ------------------------------------------------------------- prep kernel
// Sections: sincos 128 | qkv 192 | proj 64 | w1 2048 | w2 2048 | LN1 2048
// -> grid 6528. Transpose tile = 64k x 256n; dst k-blocked [K/64][N][64].
__global__ __launch_bounds__(256) void k_prep(
    const float* __restrict__ w_qkv, const float* __restrict__ w_proj,
    const float* __restrict__ w1, const float* __restrict__ w2,
    u16* __restrict__ wqkvT, u16* __restrict__ wprojT,
    u16* __restrict__ w1T, u16* __restrict__ w2T,
    float* __restrict__ st, float* __restrict__ ct,
    const float* __restrict__ x, const float* __restrict__ ln1_g,
    const float* __restrict__ ln1_b, u16* __restrict__ h1)
{
  const int tid = threadIdx.x;
  int bid = blockIdx.x;
  if (bid < 128){
    const int idx = bid * 256 + tid;
    const int t = idx >> 5, i = idx & 31;
    const float inv = expf((float)(2 * i) * (-0.14391157f));
    const float ang = (float)t * inv;
    st[idx] = sinf(ang);
    ct[idx] = cosf(ang);
    return;
  }
  bid -= 128;
  if (bid >= 4352){
    // LN1 section: one block per token row
    const int row = bid - 4352;
    const int w = tid >> 6, lane = tid & 63;
    const float4 xv = *(const float4*)(x + (long)row*DD + tid*4);
    __shared__ float red[8];
    float s = xv.x + xv.y + xv.z + xv.w;
    s = waveRedSum(s);
    if (lane == 0) red[w] = s;
    __syncthreads();
    const float mean = (red[0]+red[1]+red[2]+red[3]) * (1.f/1024.f);
    const float d0 = xv.x-mean, d1 = xv.y-mean, d2 = xv.z-mean, d3 = xv.w-mean;
    float vs = d0*d0 + d1*d1 + d2*d2 + d3*d3;
    vs = waveRedSum(vs);
    if (lane == 0) red[4+w] = vs;
    __syncthreads();
    const float var = (red[4]+red[5]+red[6]+red[7]) * (1.f/1024.f);
    const float inv = rsqrtf(var + 1e-5f);
    const int c = tid*4;
    short4v p;
    p[0] = (short)f2bf(d0*inv*ln1_g[c+0] + ln1_b[c+0]);
    p[1] = (short)f2bf(d1*inv*ln1_g[c+1] + ln1_b[c+1]);
    p[2] = (short)f2bf(d2*inv*ln1_g[c+2] + ln1_b[c+2]);
    p[3] = (short)f2bf(d3*inv*ln1_g[c+3] + ln1_b[c+3]);
    *(short4v*)(h1 + (long)row*DD + c) = p;
    return;
  }
  const float* src; u16* dst; int N, nnx, tile;
  long zoff = 0;
  if (bid < 192){
    src = w_qkv; dst = wqkvT; N = 3*DD; nnx = 12; tile = bid;
  } else if (bid < 256){
    src = w_proj; dst = wprojT; N = DD; nnx = 4; tile = bid - 192;
  } else if (bid < 2304){
    const int b2 = bid - 256;
    src = w1; dst = w1T; N = DFF; nnx = 16; tile = b2 & 255;
    zoff = (long)(b2 >> 8) * DD * DFF;
  } else {
    const int b2 = bid - 2304;
    src = w2; dst = w2T; N = DD; nnx = 4; tile = b2 & 255;
    zoff = (long)(b2 >> 8) * DFF * DD;
  }
  const int n0 = (tile % nnx) * 256, k0 = (tile / nnx) * 64;

  __shared__ u16 tb[64*258];   // [k][n] bf16, row pitch 258
#pragma unroll
  for (int i = 0; i < 16; ++i){
    const int r = i*4 + (tid >> 6);
    const int c = (tid & 63) * 4;
    const float4 v = *(const float4*)(src + zoff + (long)(k0 + r)*N + n0 + c);
    const u32 lo = (u32)f2bf(v.x) | ((u32)f2bf(v.y) << 16);
    const u32 hi = (u32)f2bf(v.z) | ((u32)f2bf(v.w) << 16);
    *(u32*)(tb + r*258 + c)     = lo;
    *(u32*)(tb + r*258 + c + 2) = hi;
  }
  __syncthreads();
  const int koct = tid & 7;
  u16* dpb = dst + zoff + (long)k0*N + (long)n0*64 + koct*8;
#pragma unroll
  for (int q = 0; q < 8; ++q){
    const int n = q*32 + (tid >> 3);
    short8 o;
#pragma unroll
    for (int j = 0; j < 8; ++j)
      o[j] = (short)tb[(koct*8 + j)*258 + n];
    *(short8*)(dpb + (long)n*64) = o;
  }
}

// ---------------------------------------------------------------- GEMM core
// C 128x128 tile, 4 waves 2x2, A bf16 [M,K] (opt row-gather),
// B bf16 k-blocked [K/64][BN][64]. BK=64, double-buffered, counted vmcnt,
// T2 XOR-swizzle. LDS layout identical to the [N][K] variant.
template<bool GATHER>
__device__ __forceinline__ void gemm_core5(
    const u16* __restrict__ A, int lda, const int* __restrict__ rowlist,
    const u16* __restrict__ Bt, int BN, int K, int kstart, int row0, int col0,
    u16* As0, u16* Bs0, u16* As1, u16* Bs1, f32x16 acc[2][2])
{
  const int tid = threadIdx.x;
  const int lane = tid & 63;
  const int w = tid >> 6;
  const int wr = w >> 1, wc = w & 1;
  const int l31 = lane & 31, l5 = lane >> 5;
  const int rr8 = lane >> 3;
  const int cc8 = ((lane & 7) ^ rr8) * 8;

  const u16* Aq[4];
  const u16* Bq[4];
  int coff[4];
#pragma unroll
  for (int j2 = 0; j2 < 4; ++j2){
    const int j = w + 4*j2;
    long ar;
    if constexpr (GATHER) ar = rowlist[row0 + j*8 + rr8];
    else                  ar = row0 + j*8 + rr8;
    Aq[j2] = A + ar*(long)lda + kstart + cc8;
    Bq[j2] = Bt + (long)kstart*BN + (long)(col0 + j*8 + rr8)*64 + cc8;
    coff[j2] = j*512;
  }

  const int swz = (l31 & 7) * 8;

#define STAGE5(AS, BS, KOFF) \
  _Pragma("unroll") \
  for (int j2 = 0; j2 < 4; ++j2){ \
    gl16(Aq[j2] + (KOFF), (AS) + coff[j2]); \
    gl16(Bq[j2] + (long)(KOFF)*BN, (BS) + coff[j2]); \
  }

#define COMPUTE5(AS, BS) \
  _Pragma("unroll") \
  for (int s = 0; s < 4; ++s){ \
    short8 aF[2], bF[2]; \
    const int cread = ((s*16 + l5*8) ^ swz); \
    _Pragma("unroll") \
    for (int mi = 0; mi < 2; ++mi) \
      aF[mi] = *(const short8*)((AS) + (wr*64 + mi*32 + l31)*64 + cread); \
    _Pragma("unroll") \
    for (int ni = 0; ni < 2; ++ni) \
      bF[ni] = *(const short8*)((BS) + (wc*64 + ni*32 + l31)*64 + cread); \
    _Pragma("unroll") \
    for (int mi = 0; mi < 2; ++mi) \
      _Pragma("unroll") \
      for (int ni = 0; ni < 2; ++ni) \
        acc[mi][ni] = __builtin_amdgcn_mfma_f32_32x32x16_bf16(aF[mi], bF[ni], acc[mi][ni], 0, 0, 0); \
  }

  STAGE5(As0, Bs0, 0)

  for (int k0 = 0; k0 < K; k0 += 128){
    STAGE5(As1, Bs1, k0 + 64)
    asm volatile("s_waitcnt vmcnt(8)" ::: "memory");
    __builtin_amdgcn_s_barrier();
    __builtin_amdgcn_sched_barrier(0);
    COMPUTE5(As0, Bs0)
    __builtin_amdgcn_s_barrier();
    if (k0 + 128 < K){
      STAGE5(As0, Bs0, k0 + 128)
      asm volatile("s_waitcnt vmcnt(8)" ::: "memory");
    } else {
      asm volatile("s_waitcnt vmcnt(0)" ::: "memory");
    }
    __builtin_amdgcn_s_barrier();
    __builtin_amdgcn_sched_barrier(0);
    COMPUTE5(As1, Bs1)
    __builtin_amdgcn_s_barrier();
  }
#undef STAGE5
#undef COMPUTE5
}

#define GEMM_PRE4 \
  __shared__ u16 As0[128*64], Bs0[128*64], As1[128*64], Bs1[128*64]; \
  f32x16 acc[2][2]; \
  _Pragma("unroll") for (int i = 0; i < 2; ++i) \
  _Pragma("unroll") for (int j = 0; j < 2; ++j) \
  _Pragma("unroll") for (int q = 0; q < 16; ++q) acc[i][j][q] = 0.f;

#define GEMM_EPI4_VARS \
  const int lane = threadIdx.x & 63; \
  const int wv = threadIdx.x >> 6;   \
  const int wr = wv >> 1, wc = wv & 1; \
  const int l31 = lane & 31, l5 = lane >> 5;

#define ROW4(mi, r) (row0 + wr*64 + (mi)*32 + ((r)&3) + (((r)>>2)<<3) + l5*4)
#define COL4(ni)    (col0 + wc*64 + (ni)*32 + l31)

// ---------------------------------------------------------------- kernels
// QKV GEMM with fused RoPE epilogue. pcol 0-7: q heads, 8-15: k heads,
// 16-23: v (plain bf16 store to v_row).
__global__ __launch_bounds__(256) void k_gemm_qkv(const u16* __restrict__ h1,
    const u16* __restrict__ wqT, const float* __restrict__ st,
    const float* __restrict__ ct, u16* __restrict__ q_r, u16* __restrict__ k_r,
    u16* __restrict__ v_row)
{
  GEMM_PRE4
  const int id = blockIdx.x;
  const int pcol = id % 24, mt = id / 24;
  const int row0 = mt*128, col0 = pcol*128;
  gemm_core5<false>(h1, DD, nullptr, wqT, 3*DD, DD, 0, row0, col0, As0, Bs0, As1, Bs1, acc);
  GEMM_EPI4_VARS
  if (pcol < 16){
    const int isk = pcol >> 3;
    const int h = (pcol & 7)*2 + wc;
    u16* dstbase = isk ? k_r : q_r;
    const float qs = isk ? 1.f : 0.125f;
#pragma unroll
    for (int mi = 0; mi < 2; ++mi)
#pragma unroll
      for (int r = 0; r < 16; ++r){
        const int rr = ROW4(mi, r);
        const int b = rr >> 10, t = rr & (TB-1);
        const float sv = st[t*32 + l31], cv = ct[t*32 + l31];
        const float a0 = acc[mi][0][r], a1 = acc[mi][1][r];
        const float o1 = (a0*cv - a1*sv) * qs;
        const float o2 = (a1*cv + a0*sv) * qs;
        u16* dst = dstbase + ((long)(b*16 + h)*TB + t)*64 + l31;
        dst[0]  = f2bf(o1);
        dst[32] = f2bf(o2);
      }
  } else {
    const int cb = (pcol - 16)*128 + wc*64;
#pragma unroll
    for (int mi = 0; mi < 2; ++mi)
#pragma unroll
      for (int ni = 0; ni < 2; ++ni)
#pragma unroll
        for (int r = 0; r < 16; ++r){
          const int rr = ROW4(mi, r);
          v_row[(long)rr*DD + cb + ni*32 + l31] = f2bf(acc[mi][ni][r]);
        }
  }
}

// transpose V: v_row [b*T+t][D] -> v_t [bh][dh][t]
__global__ __launch_bounds__(256) void k_vt(const u16* __restrict__ v_row,
    u16* __restrict__ v_t)
{
  __shared__ u16 vt[64*72];
  const int tid = threadIdx.x;
  const int bh = blockIdx.y, b = bh >> 4, h = bh & 15;
  const int t0 = blockIdx.x * 64;
  const int tl = tid >> 2, qq = tid & 3;
  const int t = t0 + tl;
  const long row = (long)(b*TB + t) * DD + h*64;
  const short8 w0 = *(const short8*)(v_row + row + qq*16);
  const short8 w1 = *(const short8*)(v_row + row + qq*16 + 8);
#pragma unroll
  for (int j = 0; j < 8; ++j){
    vt[(qq*16 + j)*72 + tl]     = (u16)w0[j];
    vt[(qq*16 + 8 + j)*72 + tl] = (u16)w1[j];
  }
  __syncthreads();
  const int dh = tid >> 2, seg = tid & 3;
  const short8 r0 = *(const short8*)(vt + dh*72 + seg*16);
  const short8 r1 = *(const short8*)(vt + dh*72 + seg*16 + 8);
  u16* vp = v_t + ((long)bh*64 + dh)*TB + t0 + seg*16;
  *(short8*)vp = r0; *(short8*)(vp + 8) = r1;
}

// split-KV flash attention: grid (qtile 8, bh 32, chunk 2), 8 waves.
__global__ __launch_bounds__(512) void k_attn(const u16* __restrict__ q_r,
    const u16* __restrict__ k_r, const u16* __restrict__ v_t,
    u16* __restrict__ aoc, float2* __restrict__ mLc)
{
  const int qt = blockIdx.x, bh = blockIdx.y, ch = blockIdx.z;
  const int kvlen = (qt + 1) * 128;
  const int s_begin = ch * 512;
  if (s_begin >= kvlen) return;
  const int ntile = (min(s_begin + 512, kvlen) - s_begin) >> 6;

  __shared__ u16 K_lds[2][64*64];
  __shared__ u16 V_lds[2][64*64];
  __shared__ u16 P_lds[8][16*80];

  const int tid = threadIdx.x;
  const int w = tid >> 6, lane = tid & 63;
  const int l15 = lane & 15, l4 = lane >> 4;
  const int q0 = qt*128 + w*16;
  u16* P = &P_lds[w][0];

  const int srow = tid >> 3, sslot = tid & 7;
  const u16* kq = k_r + ((long)bh*TB + s_begin + srow)*64 + ((sslot ^ (srow & 7))*8);
  const u16* vq = v_t + ((long)bh*64 + srow)*TB + s_begin + ((sslot ^ (srow & 7))*8);
  u16* kD = &K_lds[0][0] + tid*8;
  u16* vD = &V_lds[0][0] + tid*8;

  const long qoff = ((long)bh*TB + q0 + l15)*64 + l4*8;
  const short8 Qf0 = *(const short8*)(q_r + qoff);
  const short8 Qf1 = *(const short8*)(q_r + qoff + 32);
  const f32x4 fz = {0.f,0.f,0.f,0.f};
  f32x4 O[4];
  float m[4], L[4];
#pragma unroll
  for (int i = 0; i < 4; ++i){ O[i] = fz; m[i] = -1e30f; L[i] = 0.f; }

  gl16(kq, kD);
  gl16(vq, vD);

  for (int t = 0; t < ntile; ++t){
    const int s0 = s_begin + t*64;
    const int cur = t & 1;
    if (t + 1 < ntile){
      gl16(kq + (t+1)*4096, kD + (cur^1)*4096);
      gl16(vq + (t+1)*64,   vD + (cur^1)*4096);
      asm volatile("s_waitcnt vmcnt(2)" ::: "memory");
    } else {
      asm volatile("s_waitcnt vmcnt(0)" ::: "memory");
    }
    __builtin_amdgcn_s_barrier();
    __builtin_amdgcn_sched_barrier(0);
    if (s0 <= q0 + 15){
      const u16* Kb = &K_lds[cur][0];
      const u16* Vb = &V_lds[cur][0];
      f32x4 S[4];
#pragma unroll
      for (int sj = 0; sj < 4; ++sj){
        const int rl = sj*16 + l15;
        const short8 kf0 = *(const short8*)(Kb + rl*64 + ((l4 ^ (rl & 7))*8));
        const short8 kf1 = *(const short8*)(Kb + rl*64 + (((l4 + 4) ^ (rl & 7))*8));
        f32x4 z = fz;
        z = __builtin_amdgcn_mfma_f32_16x16x32_bf16(Qf0, kf0, z, 0, 0, 0);
        z = __builtin_amdgcn_mfma_f32_16x16x32_bf16(Qf1, kf1, z, 0, 0, 0);
        S[sj] = z;
      }
      if (s0 + 63 > q0){
#pragma unroll
        for (int sj = 0; sj < 4; ++sj)
#pragma unroll
          for (int r = 0; r < 4; ++r){
            const int sc = s0 + sj*16 + l15;
            const int qr = q0 + l4*4 + r;
            if (sc > qr) S[sj][r] = -1e30f;
          }
      }
      float vm[4];
#pragma unroll
      for (int r = 0; r < 4; ++r){
        vm[r] = fmaxf(fmaxf(S[0][r], S[1][r]), fmaxf(S[2][r], S[3][r]));
        vm[r] = fmaxf(vm[r], __shfl_xor(vm[r], 1));
        vm[r] = fmaxf(vm[r], __shfl_xor(vm[r], 2));
        vm[r] = fmaxf(vm[r], __shfl_xor(vm[r], 4));
        vm[r] = fmaxf(vm[r], __shfl_xor(vm[r], 8));
      }
      float corr[4], ls[4];
#pragma unroll
      for (int r = 0; r < 4; ++r){
        const float mn = fmaxf(m[r], vm[r]);
        corr[r] = __expf(m[r] - mn);
        m[r] = mn;
        ls[r] = 0.f;
      }
#pragma unroll
      for (int sj = 0; sj < 4; ++sj)
#pragma unroll
        for (int r = 0; r < 4; ++r){
          const float pv = __expf(S[sj][r] - m[r]);
          S[sj][r] = pv;
          ls[r] += pv;
        }
#pragma unroll
      for (int r = 0; r < 4; ++r){
        ls[r] += __shfl_xor(ls[r], 1);
        ls[r] += __shfl_xor(ls[r], 2);
        ls[r] += __shfl_xor(ls[r], 4);
        ls[r] += __shfl_xor(ls[r], 8);
        L[r] = L[r]*corr[r] + ls[r];
      }
#pragma unroll
      for (int nj = 0; nj < 4; ++nj)
#pragma unroll
        for (int r = 0; r < 4; ++r)
          O[nj][r] *= corr[r];
#pragma unroll
      for (int sj = 0; sj < 4; ++sj)
#pragma unroll
        for (int r = 0; r < 4; ++r)
          P[(l4*4 + r)*80 + sj*16 + l15] = f2bf(S[sj][r]);
      asm volatile("s_waitcnt lgkmcnt(0)" ::: "memory");
      __builtin_amdgcn_sched_barrier(0);
      const short8 pf0 = *(const short8*)(P + l15*80 + l4*8);
      const short8 pf1 = *(const short8*)(P + l15*80 + 32 + l4*8);
#pragma unroll
      for (int nj = 0; nj < 4; ++nj){
        const int rl = nj*16 + l15;
        const short8 vf0 = *(const short8*)(Vb + rl*64 + ((l4 ^ (rl & 7))*8));
        const short8 vf1 = *(const short8*)(Vb + rl*64 + (((l4 + 4) ^ (rl & 7))*8));
        O[nj] = __builtin_amdgcn_mfma_f32_16x16x32_bf16(pf0, vf0, O[nj], 0, 0, 0);
        O[nj] = __builtin_amdgcn_mfma_f32_16x16x32_bf16(pf1, vf1, O[nj], 0, 0, 0);
      }
    }
    __builtin_amdgcn_sched_barrier(0);
    __builtin_amdgcn_s_barrier();
  }
  const long obase = ((long)(bh*8 + qt)*2 + ch) * 8192;
#pragma unroll
  for (int nj = 0; nj < 4; ++nj)
#pragma unroll
    for (int r = 0; r < 4; ++r)
      aoc[obase + (long)(w*16 + l4*4 + r)*64 + nj*16 + l15] = f2bf(O[nj][r]);
  if (l15 == 0){
#pragma unroll
    for (int r = 0; r < 4; ++r)
      mLc[((long)(bh*8 + qt)*2 + ch)*128 + w*16 + l4*4 + r] = make_float2(m[r], L[r]);
  }
}

__global__ __launch_bounds__(256) void k_attn_comb(const u16* __restrict__ aoc,
    const float2* __restrict__ mLc, u16* __restrict__ ao)
{
  const int bq = blockIdx.x;
  const int qt = bq & 7, bh = bq >> 3, b = bh >> 4, h = bh & 15;
  const int nc2 = (qt >= 4);
  const int d = threadIdx.x & 63;
  const int r0 = threadIdx.x >> 6;
  const long base = (long)bq * 2 * 8192;
  const long mbase = (long)bq * 2 * 128;
  for (int rp = 0; rp < 32; ++rp){
    const int r = rp*4 + r0;
    const float2 ml0 = mLc[mbase + r];
    float o, Lg;
    if (nc2){
      const float2 ml1 = mLc[mbase + 128 + r];
      const float mg = fmaxf(ml0.x, ml1.x);
      const float w0 = __expf(ml0.x - mg), w1 = __expf(ml1.x - mg);
      o  = w0 * bf2f(aoc[base + (long)r*64 + d]) + w1 * bf2f(aoc[base + 8192 + (long)r*64 + d]);
      Lg = w0 * ml0.y + w1 * ml1.y;
    } else {
      o  = bf2f(aoc[base + (long)r*64 + d]);
      Lg = ml0.y;
    }
    const int t = qt*128 + r;
    ao[((long)b*TB + t)*DD + h*64 + d] = f2bf(o / Lg);
  }
}

__global__ __launch_bounds__(256) void k_gemm_proj(const u16* __restrict__ ao,
    const u16* __restrict__ wpT, const float* __restrict__ x, float* __restrict__ out)
{
  GEMM_PRE4
  const int id = blockIdx.x;
  const int pcol = id % 8, mt = id / 8;
  const int row0 = mt*128, col0 = pcol*128;
  gemm_core5<false>(ao, DD, nullptr, wpT, DD, DD, 0, row0, col0, As0, Bs0, As1, Bs1, acc);
  GEMM_EPI4_VARS
#pragma unroll
  for (int mi = 0; mi < 2; ++mi)
#pragma unroll
    for (int ni = 0; ni < 2; ++ni)
#pragma unroll
      for (int r = 0; r < 16; ++r){
        const int rr = ROW4(mi, r);
        const int cc = COL4(ni);
        out[(long)rr*DD + cc] = x[(long)rr*DD + cc] + acc[mi][ni][r];
      }
}

// fused LN2 + noisy top-2 router; also inits slot_of to -1.
__global__ __launch_bounds__(256) void k_ln2r(const float* __restrict__ x,
    const float* __restrict__ g, const float* __restrict__ bb,
    const float* __restrict__ w_rl, const float* __restrict__ b_rl,
    const float* __restrict__ w_rn, const float* __restrict__ b_rn,
    const float* __restrict__ noise, u16* __restrict__ h2b,
    int2* __restrict__ tok_e, float2* __restrict__ tok_g, int* __restrict__ slot_of)
{
  const int row = blockIdx.x, tid = threadIdx.x;
  const int w = tid >> 6, lane = tid & 63;
  const float4 xv = *(const float4*)(x + (long)row*DD + tid*4);
  __shared__ float red[8];
  __shared__ float red2[4][16];
  float s = xv.x + xv.y + xv.z + xv.w;
  s = waveRedSum(s);
  if (lane == 0) red[w] = s;
  __syncthreads();
  const float mean = (red[0]+red[1]+red[2]+red[3]) * (1.f/1024.f);
  const float d0 = xv.x-mean, d1 = xv.y-mean, d2 = xv.z-mean, d3 = xv.w-mean;
  float vs = d0*d0 + d1*d1 + d2*d2 + d3*d3;
  vs = waveRedSum(vs);
  if (lane == 0) red[4+w] = vs;
  __syncthreads();
  const float var = (red[4]+red[5]+red[6]+red[7]) * (1.f/1024.f);
  const float inv = rsqrtf(var + 1e-5f);
  const int c = tid*4;
  const float hv[4] = {
    d0*inv*g[c+0] + bb[c+0], d1*inv*g[c+1] + bb[c+1],
    d2*inv*g[c+2] + bb[c+2], d3*inv*g[c+3] + bb[c+3]};
  short4v p;
#pragma unroll
  for (int j = 0; j < 4; ++j) p[j] = (short)f2bf(hv[j]);
  *(short4v*)(h2b + (long)row*DD + c) = p;

  float accl[8] = {0,0,0,0,0,0,0,0};
  float accn[8] = {0,0,0,0,0,0,0,0};
#pragma unroll
  for (int j = 0; j < 4; ++j){
    const int k = c + j;
    const float4 a = *(const float4*)(w_rl + k*8);
    const float4 b = *(const float4*)(w_rl + k*8 + 4);
    accl[0] += hv[j]*a.x; accl[1] += hv[j]*a.y; accl[2] += hv[j]*a.z; accl[3] += hv[j]*a.w;
    accl[4] += hv[j]*b.x; accl[5] += hv[j]*b.y; accl[6] += hv[j]*b.z; accl[7] += hv[j]*b.w;
    const float4 cc = *(const float4*)(w_rn + k*8);
    const float4 d = *(const float4*)(w_rn + k*8 + 4);
    accn[0] += hv[j]*cc.x; accn[1] += hv[j]*cc.y; accn[2] += hv[j]*cc.z; accn[3] += hv[j]*cc.w;
    accn[4] += hv[j]*d.x; accn[5] += hv[j]*d.y; accn[6] += hv[j]*d.z; accn[7] += hv[j]*d.w;
  }
#pragma unroll
  for (int e = 0; e < 8; ++e){ accl[e] = waveRedSum(accl[e]); accn[e] = waveRedSum(accn[e]); }
  if (lane == 0){
#pragma unroll
    for (int e = 0; e < 8; ++e){ red2[w][e] = accl[e]; red2[w][8+e] = accn[e]; }
  }
  __syncthreads();
  if (tid == 0){
    float nv[8];
#pragma unroll
    for (int e = 0; e < 8; ++e){
      const float lr = red2[0][e]+red2[1][e]+red2[2][e]+red2[3][e] + b_rl[e];
      const float lnv = red2[0][8+e]+red2[1][8+e]+red2[2][8+e]+red2[3][8+e] + b_rn[e];
      const float sp = fmaxf(lnv, 0.f) + log1pf(expf(-fabsf(lnv)));
      nv[e] = lr + noise[row*8 + e] * sp;
    }
    int bi = 0; float bvv = nv[0];
#pragma unroll
    for (int e = 1; e < 8; ++e) if (nv[e] > bvv){ bvv = nv[e]; bi = e; }
    int si = (bi == 0) ? 1 : 0;
    float sv = nv[si];
#pragma unroll
    for (int e = 0; e < 8; ++e) if (e != bi && nv[e] > sv){ sv = nv[e]; si = e; }
    const float tt = expf(sv - bvv);
    tok_e[row] = make_int2(bi, si);
    tok_g[row] = make_float2(1.f/(1.f + tt), tt/(1.f + tt));
    slot_of[row*2]     = -1;
    slot_of[row*2 + 1] = -1;
  }
}

__global__ __launch_bounds__(256) void k_assign(const int2* __restrict__ tok_e,
    int* __restrict__ expert_tok, int* __restrict__ slot_of)
{
  const int e = blockIdx.x, tid = threadIdx.x;
  __shared__ int cnt[256];
  expert_tok[e*CAPN + tid] = 0;
  expert_tok[e*CAPN + 256 + tid] = 0;
  int which[8]; int c = 0;
  const int t0 = tid * 8;
#pragma unroll
  for (int j = 0; j < 8; ++j){
    const int2 te = tok_e[t0 + j];
    int wj = -1;
    if (te.x == e) wj = 0; else if (te.y == e) wj = 1;
    which[j] = wj;
    c += (wj >= 0) ? 1 : 0;
  }
  cnt[tid] = c;
  __syncthreads();
  if (tid == 0){
    int run = 0;
    for (int i = 0; i < 256; ++i){ const int v = cnt[i]; cnt[i] = run; run += v; }
  }
  __syncthreads();
  int pos = cnt[tid];
#pragma unroll
  for (int j = 0; j < 8; ++j){
    if (which[j] >= 0){
      if (pos < CAPN){
        expert_tok[e*CAPN + pos] = t0 + j;
        slot_of[(t0 + j)*2 + which[j]] = e*CAPN + pos;
      }
      ++pos;
    }
  }
}

// ffn1: 1024 blocks, XCD-chunked: each XCD owns one expert; mt innermost.
__global__ __launch_bounds__(256) void k_ffn1(const u16* __restrict__ h2b,
    const u16* __restrict__ w1T, const float* __restrict__ b1,
    const int* __restrict__ expert_tok, u16* __restrict__ act)
{
  GEMM_PRE4
  const int id = blockIdx.x;
  const int chunk = (id & 7) * 128 + (id >> 3);
  const int mt = chunk & 3, pcol = (chunk >> 2) & 31, z = chunk >> 7;
  const int row0 = mt*128, col0 = pcol*128;
  gemm_core5<true>(h2b, DD, expert_tok + z*CAPN, w1T + (long)z*DD*DFF, DFF, DD, 0,
                   row0, col0, As0, Bs0, As1, Bs1, acc);
  GEMM_EPI4_VARS
#pragma unroll
  for (int mi = 0; mi < 2; ++mi)
#pragma unroll
    for (int ni = 0; ni < 2; ++ni)
#pragma unroll
      for (int r = 0; r < 16; ++r){
        const int rr = ROW4(mi, r);
        const int cc = COL4(ni);
        const float val = fmaxf(acc[mi][ni][r] + b1[z*DFF + cc], 0.f);
        act[((long)z*CAPN + rr)*DFF + cc] = f2bf(val);
      }
}

// ffn2: split-K=2, 512 blocks, XCD-chunked (expert per XCD); bf16 partials.
__global__ __launch_bounds__(256) void k_ffn2(const u16* __restrict__ act,
    const u16* __restrict__ w2T, u16* __restrict__ partial)
{
  GEMM_PRE4
  const int id = blockIdx.x;
  const int chunk = (id & 7) * 64 + (id >> 3);
  const int ks = chunk & 1, mt = (chunk >> 1) & 3, pcol = (chunk >> 3) & 7, z = chunk >> 6;
  const int row0 = mt*128, col0 = pcol*128;
  gemm_core5<false>(act + (long)z*CAPN*DFF, DFF, nullptr,
                    w2T + (long)z*DFF*DD, DD, 2048, ks*2048,
                    row0, col0, As0, Bs0, As1, Bs1, acc);
  GEMM_EPI4_VARS
  u16* pp = partial + (long)ks*NEXPERT*CAPN*DD;
#pragma unroll
  for (int mi = 0; mi < 2; ++mi)
#pragma unroll
    for (int ni = 0; ni < 2; ++ni)
#pragma unroll
      for (int r = 0; r < 16; ++r){
        const int rr = ROW4(mi, r);
        const int cc = COL4(ni);
        pp[((long)z*CAPN + rr)*DD + cc] = f2bf(acc[mi][ni][r]);
      }
}

// reduce bf16 split-K partials + bias + gate + residual add
__global__ __launch_bounds__(256) void k_combine(float* __restrict__ out,
    const int* __restrict__ slot_of, const float2* __restrict__ tok_g,
    const u16* __restrict__ partial, const float* __restrict__ b2)
{
  const int tok = blockIdx.x, c = threadIdx.x * 4;
  float4 o = *(float4*)(out + (long)tok*DD + c);
  const int2 ss = *(const int2*)(slot_of + tok*2);
  const float2 g = tok_g[tok];
#pragma unroll
  for (int j = 0; j < 2; ++j){
    const int s = j ? ss.y : ss.x;
    const float gw = j ? g.y : g.x;
    if (s >= 0){
      const int e = s >> 9;
      float4 a = *(const float4*)(b2 + e*DD + c);
#pragma unroll
      for (int ks = 0; ks < 2; ++ks){
        const short4v pv = *(const short4v*)(partial + (long)ks*NEXPERT*CAPN*DD + (long)s*DD + c);
        a.x += bf2f((u16)pv[0]); a.y += bf2f((u16)pv[1]);
        a.z += bf2f((u16)pv[2]); a.w += bf2f((u16)pv[3]);
      }
      o.x += gw*a.x; o.y += gw*a.y; o.z += gw*a.z; o.w += gw*a.w;
    }
  }
  *(float4*)(out + (long)tok*DD + c) = o;
}

// ---------------------------------------------------------------- launcher
extern "C" void kernel_launch(void* const* d_in, const int* in_sizes, int n_in,
                              void* d_out, int out_size, void* d_ws, size_t ws_size,
                              hipStream_t stream)
{
  (void)in_sizes; (void)n_in; (void)out_size; (void)ws_size;
  const float* x      = (const float*)d_in[0];
  const float* noise  = (const float*)d_in[1];
  const float* ln1_g  = (const float*)d_in[2];
  const float* ln1_b  = (const float*)d_in[3];
  const float* ln2_g  = (const float*)d_in[4];
  const float* ln2_b  = (const float*)d_in[5];
  const float* w_qkv  = (const float*)d_in[6];
  const float* w_proj = (const float*)d_in[7];
  const float* w_rl   = (const float*)d_in[8];
  const float* b_rl   = (const float*)d_in[9];
  const float* w_rn   = (const float*)d_in[10];
  const float* b_rn   = (const float*)d_in[11];
  const float* w1     = (const float*)d_in[12];
  const float* b1     = (const float*)d_in[13];
  const float* w2     = (const float*)d_in[14];
  const float* b2     = (const float*)d_in[15];
  float* out = (float*)d_out;

  char* p = (char*)d_ws;
  auto carve = [&](size_t bytes) -> void* {
    void* r = (void*)p;
    p += (bytes + 255) & ~(size_t)255;
    return r;
  };
  const size_t SLOT = (size_t)NTOK*DD*2;   // 4 MiB
  float* sin_t      = (float*)carve((size_t)TB*32*4);
  float* cos_t      = (float*)carve((size_t)TB*32*4);
  char*  region     = (char*)carve(SLOT*8);
  u16*   h1    = (u16*)region;                 // dead after qkv gemm
  u16*   v_row = (u16*)(region + SLOT);        // dead after k_vt
  u16*   q_r   = (u16*)(region + SLOT*4);
  u16*   k_r   = (u16*)(region + SLOT*5);
  u16*   v_t   = (u16*)(region + SLOT*6);
  u16*   ao    = (u16*)(region + SLOT*7);
  u16*   aoc   = (u16*)region;                 // slots 0-1, attn chunks
  float2* mLc  = (float2*)(region + SLOT*2);   // attn chunk stats
  u16*   act   = (u16*)region;                 // full region, MoE phase
  u16*   h2b        = (u16*)  carve((size_t)NTOK*DD*2);
  int2*  tok_e      = (int2*) carve((size_t)NTOK*8);
  float2* tok_g     = (float2*)carve((size_t)NTOK*8);
  int*   slot_of    = (int*)  carve((size_t)NTOK*2*4);
  int*   expert_tok = (int*)  carve((size_t)NEXPERT*CAPN*4);
  u16*   wqkvT      = (u16*)  carve((size_t)DD*3*DD*2);
  u16*   wprojT     = (u16*)  carve((size_t)DD*DD*2);
  u16*   w1T        = (u16*)  carve((size_t)NEXPERT*DD*DFF*2);   // 67MB
  u16*   w2T        = (u16*)  carve((size_t)NEXPERT*DFF*DD*2);   // 67MB
  u16*   partial    = (u16*)w1T;              // aliases w1T (dead after ffn1)

  k_prep   <<<6528, 256, 0, stream>>>(w_qkv, w_proj, w1, w2,
                                      wqkvT, wprojT, w1T, w2T, sin_t, cos_t,
                                      x, ln1_g, ln1_b, h1);
  k_gemm_qkv<<<384, 256, 0, stream>>>(h1, wqkvT, sin_t, cos_t, q_r, k_r, v_row);
  k_vt     <<<dim3(16, 32), 256, 0, stream>>>(v_row, v_t);
  k_attn   <<<dim3(8, 32, 2), 512, 0, stream>>>(q_r, k_r, v_t, aoc, mLc);
  k_attn_comb<<<256, 256, 0, stream>>>(aoc, mLc, ao);
  k_gemm_proj<<<128, 256, 0, stream>>>(ao, wprojT, x, out);
  k_ln2r   <<<NTOK, 256, 0, stream>>>(out, ln2_g, ln2_b, w_rl, b_rl, w_rn, b_rn,
                                      noise, h2b, tok_e, tok_g, slot_of);
  k_assign <<<NEXPERT, 256, 0, stream>>>(tok_e, expert_tok, slot_of);
  k_ffn1   <<<1024, 256, 0, stream>>>(h2b, w1T, b1, expert_tok, act);
  k_ffn2   <<<512, 256, 0, stream>>>(act, w2T, partial);
  k_combine<<<NTOK, 256, 0, stream>>>(out, slot_of, tok_g, partial, b2);
}

// Round 18
// 274.525 us; speedup vs baseline: 1.1391x; 1.1391x over previous
//
#include <hip/hip_runtime.h>

// MoE transformer block: prep(sincos+weight transposes+LN1) -> QKV(+RoPE) ->
// split-KV causal flash attn -> proj+res -> LN2+router -> assign -> expert
// FFN (bf16 split-K partials) -> combine.
// Transposed weights stored K-BLOCKED [K/64][N][64]; prep tile 64k x 256n
// with NON-TEMPORAL fp32 weight loads (bypass L2/L3 allocation).
// GEMMs: bf16 MFMA 32x32x16, 128^2 tile, BK=64, global_load_lds dwordx4,
// T2 XOR-swizzle, 2-phase double-buffered pipeline with counted vmcnt.

#define TB 1024   // T
#define DD 1024   // D
#define NTOK 2048 // B*T
#define NEXPERT 8
#define CAPN 512
#define DFF 4096

typedef __attribute__((ext_vector_type(4))) float f32x4;
typedef __attribute__((ext_vector_type(16))) float f32x16;
typedef __attribute__((ext_vector_type(8))) short short8;
typedef __attribute__((ext_vector_type(4))) short short4v;
typedef unsigned short u16;
typedef unsigned int u32;

__device__ __forceinline__ u16 f2bf(float f){
  union { float f; u32 u; } v; v.f = f;
  u32 u = v.u;
  u32 r = (u + 0x7fffu + ((u >> 16) & 1u)) >> 16;
  return (u16)r;
}
__device__ __forceinline__ float bf2f(u16 b){
  union { u32 u; float f; } v; v.u = ((u32)b) << 16;
  return v.f;
}
__device__ __forceinline__ float waveRedSum(float v){
#pragma unroll
  for (int o = 1; o < 64; o <<= 1) v += __shfl_xor(v, o);
  return v;
}

// async global->LDS, 16B per lane, wave-uniform LDS base + lane*16
__device__ __forceinline__ void gl16(const u16* g, u16* l){
  __builtin_amdgcn_global_load_lds(
    (const __attribute__((address_space(1))) u32*)g,
    (__attribute__((address_space(3))) u32*)l, 16, 0, 0);
}

// ------------------------------------------------------------- prep kernel
// Sections: sincos 128 | qkv 192 | proj 64 | w1 2048 | w2 2048 | LN1 2048
// -> grid 6528. Transpose tile = 64k x 256n; dst k-blocked [K/64][N][64].
// fp32 weight reads are non-temporal (streamed once, never reused).
__global__ __launch_bounds__(256) void k_prep(
    const float* __restrict__ w_qkv, const float* __restrict__ w_proj,
    const float* __restrict__ w1, const float* __restrict__ w2,
    u16* __restrict__ wqkvT, u16* __restrict__ wprojT,
    u16* __restrict__ w1T, u16* __restrict__ w2T,
    float* __restrict__ st, float* __restrict__ ct,
    const float* __restrict__ x, const float* __restrict__ ln1_g,
    const float* __restrict__ ln1_b, u16* __restrict__ h1)
{
  const int tid = threadIdx.x;
  int bid = blockIdx.x;
  if (bid < 128){
    const int idx = bid * 256 + tid;
    const int t = idx >> 5, i = idx & 31;
    const float inv = expf((float)(2 * i) * (-0.14391157f));
    const float ang = (float)t * inv;
    st[idx] = sinf(ang);
    ct[idx] = cosf(ang);
    return;
  }
  bid -= 128;
  if (bid >= 4352){
    // LN1 section: one block per token row
    const int row = bid - 4352;
    const int w = tid >> 6, lane = tid & 63;
    const float4 xv = *(const float4*)(x + (long)row*DD + tid*4);
    __shared__ float red[8];
    float s = xv.x + xv.y + xv.z + xv.w;
    s = waveRedSum(s);
    if (lane == 0) red[w] = s;
    __syncthreads();
    const float mean = (red[0]+red[1]+red[2]+red[3]) * (1.f/1024.f);
    const float d0 = xv.x-mean, d1 = xv.y-mean, d2 = xv.z-mean, d3 = xv.w-mean;
    float vs = d0*d0 + d1*d1 + d2*d2 + d3*d3;
    vs = waveRedSum(vs);
    if (lane == 0) red[4+w] = vs;
    __syncthreads();
    const float var = (red[4]+red[5]+red[6]+red[7]) * (1.f/1024.f);
    const float inv = rsqrtf(var + 1e-5f);
    const int c = tid*4;
    short4v p;
    p[0] = (short)f2bf(d0*inv*ln1_g[c+0] + ln1_b[c+0]);
    p[1] = (short)f2bf(d1*inv*ln1_g[c+1] + ln1_b[c+1]);
    p[2] = (short)f2bf(d2*inv*ln1_g[c+2] + ln1_b[c+2]);
    p[3] = (short)f2bf(d3*inv*ln1_g[c+3] + ln1_b[c+3]);
    *(short4v*)(h1 + (long)row*DD + c) = p;
    return;
  }
  const float* src; u16* dst; int N, nnx, tile;
  long zoff = 0;
  if (bid < 192){
    src = w_qkv; dst = wqkvT; N = 3*DD; nnx = 12; tile = bid;
  } else if (bid < 256){
    src = w_proj; dst = wprojT; N = DD; nnx = 4; tile = bid - 192;
  } else if (bid < 2304){
    const int b2 = bid - 256;
    src = w1; dst = w1T; N = DFF; nnx = 16; tile = b2 & 255;
    zoff = (long)(b2 >> 8) * DD * DFF;
  } else {
    const int b2 = bid - 2304;
    src = w2; dst = w2T; N = DD; nnx = 4; tile = b2 & 255;
    zoff = (long)(b2 >> 8) * DFF * DD;
  }
  const int n0 = (tile % nnx) * 256, k0 = (tile / nnx) * 64;

  __shared__ u16 tb[64*258];   // [k][n] bf16, row pitch 258
#pragma unroll
  for (int i = 0; i < 16; ++i){
    const int r = i*4 + (tid >> 6);
    const int c = (tid & 63) * 4;
    const f32x4 v = __builtin_nontemporal_load(
        (const f32x4*)(src + zoff + (long)(k0 + r)*N + n0 + c));
    const u32 lo = (u32)f2bf(v[0]) | ((u32)f2bf(v[1]) << 16);
    const u32 hi = (u32)f2bf(v[2]) | ((u32)f2bf(v[3]) << 16);
    *(u32*)(tb + r*258 + c)     = lo;
    *(u32*)(tb + r*258 + c + 2) = hi;
  }
  __syncthreads();
  const int koct = tid & 7;
  u16* dpb = dst + zoff + (long)k0*N + (long)n0*64 + koct*8;
#pragma unroll
  for (int q = 0; q < 8; ++q){
    const int n = q*32 + (tid >> 3);
    short8 o;
#pragma unroll
    for (int j = 0; j < 8; ++j)
      o[j] = (short)tb[(koct*8 + j)*258 + n];
    *(short8*)(dpb + (long)n*64) = o;
  }
}

// ---------------------------------------------------------------- GEMM core
// C 128x128 tile, 4 waves 2x2, A bf16 [M,K] (opt row-gather),
// B bf16 k-blocked [K/64][BN][64]. BK=64, double-buffered, counted vmcnt,
// T2 XOR-swizzle. LDS layout identical to the [N][K] variant.
template<bool GATHER>
__device__ __forceinline__ void gemm_core5(
    const u16* __restrict__ A, int lda, const int* __restrict__ rowlist,
    const u16* __restrict__ Bt, int BN, int K, int kstart, int row0, int col0,
    u16* As0, u16* Bs0, u16* As1, u16* Bs1, f32x16 acc[2][2])
{
  const int tid = threadIdx.x;
  const int lane = tid & 63;
  const int w = tid >> 6;
  const int wr = w >> 1, wc = w & 1;
  const int l31 = lane & 31, l5 = lane >> 5;
  const int rr8 = lane >> 3;
  const int cc8 = ((lane & 7) ^ rr8) * 8;

  const u16* Aq[4];
  const u16* Bq[4];
  int coff[4];
#pragma unroll
  for (int j2 = 0; j2 < 4; ++j2){
    const int j = w + 4*j2;
    long ar;
    if constexpr (GATHER) ar = rowlist[row0 + j*8 + rr8];
    else                  ar = row0 + j*8 + rr8;
    Aq[j2] = A + ar*(long)lda + kstart + cc8;
    Bq[j2] = Bt + (long)kstart*BN + (long)(col0 + j*8 + rr8)*64 + cc8;
    coff[j2] = j*512;
  }

  const int swz = (l31 & 7) * 8;

#define STAGE5(AS, BS, KOFF) \
  _Pragma("unroll") \
  for (int j2 = 0; j2 < 4; ++j2){ \
    gl16(Aq[j2] + (KOFF), (AS) + coff[j2]); \
    gl16(Bq[j2] + (long)(KOFF)*BN, (BS) + coff[j2]); \
  }

#define COMPUTE5(AS, BS) \
  _Pragma("unroll") \
  for (int s = 0; s < 4; ++s){ \
    short8 aF[2], bF[2]; \
    const int cread = ((s*16 + l5*8) ^ swz); \
    _Pragma("unroll") \
    for (int mi = 0; mi < 2; ++mi) \
      aF[mi] = *(const short8*)((AS) + (wr*64 + mi*32 + l31)*64 + cread); \
    _Pragma("unroll") \
    for (int ni = 0; ni < 2; ++ni) \
      bF[ni] = *(const short8*)((BS) + (wc*64 + ni*32 + l31)*64 + cread); \
    _Pragma("unroll") \
    for (int mi = 0; mi < 2; ++mi) \
      _Pragma("unroll") \
      for (int ni = 0; ni < 2; ++ni) \
        acc[mi][ni] = __builtin_amdgcn_mfma_f32_32x32x16_bf16(aF[mi], bF[ni], acc[mi][ni], 0, 0, 0); \
  }

  STAGE5(As0, Bs0, 0)

  for (int k0 = 0; k0 < K; k0 += 128){
    STAGE5(As1, Bs1, k0 + 64)
    asm volatile("s_waitcnt vmcnt(8)" ::: "memory");
    __builtin_amdgcn_s_barrier();
    __builtin_amdgcn_sched_barrier(0);
    COMPUTE5(As0, Bs0)
    __builtin_amdgcn_s_barrier();
    if (k0 + 128 < K){
      STAGE5(As0, Bs0, k0 + 128)
      asm volatile("s_waitcnt vmcnt(8)" ::: "memory");
    } else {
      asm volatile("s_waitcnt vmcnt(0)" ::: "memory");
    }
    __builtin_amdgcn_s_barrier();
    __builtin_amdgcn_sched_barrier(0);
    COMPUTE5(As1, Bs1)
    __builtin_amdgcn_s_barrier();
  }
#undef STAGE5
#undef COMPUTE5
}

#define GEMM_PRE4 \
  __shared__ u16 As0[128*64], Bs0[128*64], As1[128*64], Bs1[128*64]; \
  f32x16 acc[2][2]; \
  _Pragma("unroll") for (int i = 0; i < 2; ++i) \
  _Pragma("unroll") for (int j = 0; j < 2; ++j) \
  _Pragma("unroll") for (int q = 0; q < 16; ++q) acc[i][j][q] = 0.f;

#define GEMM_EPI4_VARS \
  const int lane = threadIdx.x & 63; \
  const int wv = threadIdx.x >> 6;   \
  const int wr = wv >> 1, wc = wv & 1; \
  const int l31 = lane & 31, l5 = lane >> 5;

#define ROW4(mi, r) (row0 + wr*64 + (mi)*32 + ((r)&3) + (((r)>>2)<<3) + l5*4)
#define COL4(ni)    (col0 + wc*64 + (ni)*32 + l31)

// ---------------------------------------------------------------- kernels
// QKV GEMM with fused RoPE epilogue. pcol 0-7: q heads, 8-15: k heads,
// 16-23: v (plain bf16 store to v_row).
__global__ __launch_bounds__(256) void k_gemm_qkv(const u16* __restrict__ h1,
    const u16* __restrict__ wqT, const float* __restrict__ st,
    const float* __restrict__ ct, u16* __restrict__ q_r, u16* __restrict__ k_r,
    u16* __restrict__ v_row)
{
  GEMM_PRE4
  const int id = blockIdx.x;
  const int pcol = id % 24, mt = id / 24;
  const int row0 = mt*128, col0 = pcol*128;
  gemm_core5<false>(h1, DD, nullptr, wqT, 3*DD, DD, 0, row0, col0, As0, Bs0, As1, Bs1, acc);
  GEMM_EPI4_VARS
  if (pcol < 16){
    const int isk = pcol >> 3;
    const int h = (pcol & 7)*2 + wc;
    u16* dstbase = isk ? k_r : q_r;
    const float qs = isk ? 1.f : 0.125f;
#pragma unroll
    for (int mi = 0; mi < 2; ++mi)
#pragma unroll
      for (int r = 0; r < 16; ++r){
        const int rr = ROW4(mi, r);
        const int b = rr >> 10, t = rr & (TB-1);
        const float sv = st[t*32 + l31], cv = ct[t*32 + l31];
        const float a0 = acc[mi][0][r], a1 = acc[mi][1][r];
        const float o1 = (a0*cv - a1*sv) * qs;
        const float o2 = (a1*cv + a0*sv) * qs;
        u16* dst = dstbase + ((long)(b*16 + h)*TB + t)*64 + l31;
        dst[0]  = f2bf(o1);
        dst[32] = f2bf(o2);
      }
  } else {
    const int cb = (pcol - 16)*128 + wc*64;
#pragma unroll
    for (int mi = 0; mi < 2; ++mi)
#pragma unroll
      for (int ni = 0; ni < 2; ++ni)
#pragma unroll
        for (int r = 0; r < 16; ++r){
          const int rr = ROW4(mi, r);
          v_row[(long)rr*DD + cb + ni*32 + l31] = f2bf(acc[mi][ni][r]);
        }
  }
}

// transpose V: v_row [b*T+t][D] -> v_t [bh][dh][t]
__global__ __launch_bounds__(256) void k_vt(const u16* __restrict__ v_row,
    u16* __restrict__ v_t)
{
  __shared__ u16 vt[64*72];
  const int tid = threadIdx.x;
  const int bh = blockIdx.y, b = bh >> 4, h = bh & 15;
  const int t0 = blockIdx.x * 64;
  const int tl = tid >> 2, qq = tid & 3;
  const int t = t0 + tl;
  const long row = (long)(b*TB + t) * DD + h*64;
  const short8 w0 = *(const short8*)(v_row + row + qq*16);
  const short8 w1 = *(const short8*)(v_row + row + qq*16 + 8);
#pragma unroll
  for (int j = 0; j < 8; ++j){
    vt[(qq*16 + j)*72 + tl]     = (u16)w0[j];
    vt[(qq*16 + 8 + j)*72 + tl] = (u16)w1[j];
  }
  __syncthreads();
  const int dh = tid >> 2, seg = tid & 3;
  const short8 r0 = *(const short8*)(vt + dh*72 + seg*16);
  const short8 r1 = *(const short8*)(vt + dh*72 + seg*16 + 8);
  u16* vp = v_t + ((long)bh*64 + dh)*TB + t0 + seg*16;
  *(short8*)vp = r0; *(short8*)(vp + 8) = r1;
}

// split-KV flash attention: grid (qtile 8, bh 32, chunk 2), 8 waves.
__global__ __launch_bounds__(512) void k_attn(const u16* __restrict__ q_r,
    const u16* __restrict__ k_r, const u16* __restrict__ v_t,
    u16* __restrict__ aoc, float2* __restrict__ mLc)
{
  const int qt = blockIdx.x, bh = blockIdx.y, ch = blockIdx.z;
  const int kvlen = (qt + 1) * 128;
  const int s_begin = ch * 512;
  if (s_begin >= kvlen) return;
  const int ntile = (min(s_begin + 512, kvlen) - s_begin) >> 6;

  __shared__ u16 K_lds[2][64*64];
  __shared__ u16 V_lds[2][64*64];
  __shared__ u16 P_lds[8][16*80];

  const int tid = threadIdx.x;
  const int w = tid >> 6, lane = tid & 63;
  const int l15 = lane & 15, l4 = lane >> 4;
  const int q0 = qt*128 + w*16;
  u16* P = &P_lds[w][0];

  const int srow = tid >> 3, sslot = tid & 7;
  const u16* kq = k_r + ((long)bh*TB + s_begin + srow)*64 + ((sslot ^ (srow & 7))*8);
  const u16* vq = v_t + ((long)bh*64 + srow)*TB + s_begin + ((sslot ^ (srow & 7))*8);
  u16* kD = &K_lds[0][0] + tid*8;
  u16* vD = &V_lds[0][0] + tid*8;

  const long qoff = ((long)bh*TB + q0 + l15)*64 + l4*8;
  const short8 Qf0 = *(const short8*)(q_r + qoff);
  const short8 Qf1 = *(const short8*)(q_r + qoff + 32);
  const f32x4 fz = {0.f,0.f,0.f,0.f};
  f32x4 O[4];
  float m[4], L[4];
#pragma unroll
  for (int i = 0; i < 4; ++i){ O[i] = fz; m[i] = -1e30f; L[i] = 0.f; }

  gl16(kq, kD);
  gl16(vq, vD);

  for (int t = 0; t < ntile; ++t){
    const int s0 = s_begin + t*64;
    const int cur = t & 1;
    if (t + 1 < ntile){
      gl16(kq + (t+1)*4096, kD + (cur^1)*4096);
      gl16(vq + (t+1)*64,   vD + (cur^1)*4096);
      asm volatile("s_waitcnt vmcnt(2)" ::: "memory");
    } else {
      asm volatile("s_waitcnt vmcnt(0)" ::: "memory");
    }
    __builtin_amdgcn_s_barrier();
    __builtin_amdgcn_sched_barrier(0);
    if (s0 <= q0 + 15){
      const u16* Kb = &K_lds[cur][0];
      const u16* Vb = &V_lds[cur][0];
      f32x4 S[4];
#pragma unroll
      for (int sj = 0; sj < 4; ++sj){
        const int rl = sj*16 + l15;
        const short8 kf0 = *(const short8*)(Kb + rl*64 + ((l4 ^ (rl & 7))*8));
        const short8 kf1 = *(const short8*)(Kb + rl*64 + (((l4 + 4) ^ (rl & 7))*8));
        f32x4 z = fz;
        z = __builtin_amdgcn_mfma_f32_16x16x32_bf16(Qf0, kf0, z, 0, 0, 0);
        z = __builtin_amdgcn_mfma_f32_16x16x32_bf16(Qf1, kf1, z, 0, 0, 0);
        S[sj] = z;
      }
      if (s0 + 63 > q0){
#pragma unroll
        for (int sj = 0; sj < 4; ++sj)
#pragma unroll
          for (int r = 0; r < 4; ++r){
            const int sc = s0 + sj*16 + l15;
            const int qr = q0 + l4*4 + r;
            if (sc > qr) S[sj][r] = -1e30f;
          }
      }
      float vm[4];
#pragma unroll
      for (int r = 0; r < 4; ++r){
        vm[r] = fmaxf(fmaxf(S[0][r], S[1][r]), fmaxf(S[2][r], S[3][r]));
        vm[r] = fmaxf(vm[r], __shfl_xor(vm[r], 1));
        vm[r] = fmaxf(vm[r], __shfl_xor(vm[r], 2));
        vm[r] = fmaxf(vm[r], __shfl_xor(vm[r], 4));
        vm[r] = fmaxf(vm[r], __shfl_xor(vm[r], 8));
      }
      float corr[4], ls[4];
#pragma unroll
      for (int r = 0; r < 4; ++r){
        const float mn = fmaxf(m[r], vm[r]);
        corr[r] = __expf(m[r] - mn);
        m[r] = mn;
        ls[r] = 0.f;
      }
#pragma unroll
      for (int sj = 0; sj < 4; ++sj)
#pragma unroll
        for (int r = 0; r < 4; ++r){
          const float pv = __expf(S[sj][r] - m[r]);
          S[sj][r] = pv;
          ls[r] += pv;
        }
#pragma unroll
      for (int r = 0; r < 4; ++r){
        ls[r] += __shfl_xor(ls[r], 1);
        ls[r] += __shfl_xor(ls[r], 2);
        ls[r] += __shfl_xor(ls[r], 4);
        ls[r] += __shfl_xor(ls[r], 8);
        L[r] = L[r]*corr[r] + ls[r];
      }
#pragma unroll
      for (int nj = 0; nj < 4; ++nj)
#pragma unroll
        for (int r = 0; r < 4; ++r)
          O[nj][r] *= corr[r];
#pragma unroll
      for (int sj = 0; sj < 4; ++sj)
#pragma unroll
        for (int r = 0; r < 4; ++r)
          P[(l4*4 + r)*80 + sj*16 + l15] = f2bf(S[sj][r]);
      asm volatile("s_waitcnt lgkmcnt(0)" ::: "memory");
      __builtin_amdgcn_sched_barrier(0);
      const short8 pf0 = *(const short8*)(P + l15*80 + l4*8);
      const short8 pf1 = *(const short8*)(P + l15*80 + 32 + l4*8);
#pragma unroll
      for (int nj = 0; nj < 4; ++nj){
        const int rl = nj*16 + l15;
        const short8 vf0 = *(const short8*)(Vb + rl*64 + ((l4 ^ (rl & 7))*8));
        const short8 vf1 = *(const short8*)(Vb + rl*64 + (((l4 + 4) ^ (rl & 7))*8));
        O[nj] = __builtin_amdgcn_mfma_f32_16x16x32_bf16(pf0, vf0, O[nj], 0, 0, 0);
        O[nj] = __builtin_amdgcn_mfma_f32_16x16x32_bf16(pf1, vf1, O[nj], 0, 0, 0);
      }
    }
    __builtin_amdgcn_sched_barrier(0);
    __builtin_amdgcn_s_barrier();
  }
  const long obase = ((long)(bh*8 + qt)*2 + ch) * 8192;
#pragma unroll
  for (int nj = 0; nj < 4; ++nj)
#pragma unroll
    for (int r = 0; r < 4; ++r)
      aoc[obase + (long)(w*16 + l4*4 + r)*64 + nj*16 + l15] = f2bf(O[nj][r]);
  if (l15 == 0){
#pragma unroll
    for (int r = 0; r < 4; ++r)
      mLc[((long)(bh*8 + qt)*2 + ch)*128 + w*16 + l4*4 + r] = make_float2(m[r], L[r]);
  }
}

__global__ __launch_bounds__(256) void k_attn_comb(const u16* __restrict__ aoc,
    const float2* __restrict__ mLc, u16* __restrict__ ao)
{
  const int bq = blockIdx.x;
  const int qt = bq & 7, bh = bq >> 3, b = bh >> 4, h = bh & 15;
  const int nc2 = (qt >= 4);
  const int d = threadIdx.x & 63;
  const int r0 = threadIdx.x >> 6;
  const long base = (long)bq * 2 * 8192;
  const long mbase = (long)bq * 2 * 128;
  for (int rp = 0; rp < 32; ++rp){
    const int r = rp*4 + r0;
    const float2 ml0 = mLc[mbase + r];
    float o, Lg;
    if (nc2){
      const float2 ml1 = mLc[mbase + 128 + r];
      const float mg = fmaxf(ml0.x, ml1.x);
      const float w0 = __expf(ml0.x - mg), w1 = __expf(ml1.x - mg);
      o  = w0 * bf2f(aoc[base + (long)r*64 + d]) + w1 * bf2f(aoc[base + 8192 + (long)r*64 + d]);
      Lg = w0 * ml0.y + w1 * ml1.y;
    } else {
      o  = bf2f(aoc[base + (long)r*64 + d]);
      Lg = ml0.y;
    }
    const int t = qt*128 + r;
    ao[((long)b*TB + t)*DD + h*64 + d] = f2bf(o / Lg);
  }
}

__global__ __launch_bounds__(256) void k_gemm_proj(const u16* __restrict__ ao,
    const u16* __restrict__ wpT, const float* __restrict__ x, float* __restrict__ out)
{
  GEMM_PRE4
  const int id = blockIdx.x;
  const int pcol = id % 8, mt = id / 8;
  const int row0 = mt*128, col0 = pcol*128;
  gemm_core5<false>(ao, DD, nullptr, wpT, DD, DD, 0, row0, col0, As0, Bs0, As1, Bs1, acc);
  GEMM_EPI4_VARS
#pragma unroll
  for (int mi = 0; mi < 2; ++mi)
#pragma unroll
    for (int ni = 0; ni < 2; ++ni)
#pragma unroll
      for (int r = 0; r < 16; ++r){
        const int rr = ROW4(mi, r);
        const int cc = COL4(ni);
        out[(long)rr*DD + cc] = x[(long)rr*DD + cc] + acc[mi][ni][r];
      }
}

// fused LN2 + noisy top-2 router; also inits slot_of to -1.
__global__ __launch_bounds__(256) void k_ln2r(const float* __restrict__ x,
    const float* __restrict__ g, const float* __restrict__ bb,
    const float* __restrict__ w_rl, const float* __restrict__ b_rl,
    const float* __restrict__ w_rn, const float* __restrict__ b_rn,
    const float* __restrict__ noise, u16* __restrict__ h2b,
    int2* __restrict__ tok_e, float2* __restrict__ tok_g, int* __restrict__ slot_of)
{
  const int row = blockIdx.x, tid = threadIdx.x;
  const int w = tid >> 6, lane = tid & 63;
  const float4 xv = *(const float4*)(x + (long)row*DD + tid*4);
  __shared__ float red[8];
  __shared__ float red2[4][16];
  float s = xv.x + xv.y + xv.z + xv.w;
  s = waveRedSum(s);
  if (lane == 0) red[w] = s;
  __syncthreads();
  const float mean = (red[0]+red[1]+red[2]+red[3]) * (1.f/1024.f);
  const float d0 = xv.x-mean, d1 = xv.y-mean, d2 = xv.z-mean, d3 = xv.w-mean;
  float vs = d0*d0 + d1*d1 + d2*d2 + d3*d3;
  vs = waveRedSum(vs);
  if (lane == 0) red[4+w] = vs;
  __syncthreads();
  const float var = (red[4]+red[5]+red[6]+red[7]) * (1.f/1024.f);
  const float inv = rsqrtf(var + 1e-5f);
  const int c = tid*4;
  const float hv[4] = {
    d0*inv*g[c+0] + bb[c+0], d1*inv*g[c+1] + bb[c+1],
    d2*inv*g[c+2] + bb[c+2], d3*inv*g[c+3] + bb[c+3]};
  short4v p;
#pragma unroll
  for (int j = 0; j < 4; ++j) p[j] = (short)f2bf(hv[j]);
  *(short4v*)(h2b + (long)row*DD + c) = p;

  float accl[8] = {0,0,0,0,0,0,0,0};
  float accn[8] = {0,0,0,0,0,0,0,0};
#pragma unroll
  for (int j = 0; j < 4; ++j){
    const int k = c + j;
    const float4 a = *(const float4*)(w_rl + k*8);
    const float4 b = *(const float4*)(w_rl + k*8 + 4);
    accl[0] += hv[j]*a.x; accl[1] += hv[j]*a.y; accl[2] += hv[j]*a.z; accl[3] += hv[j]*a.w;
    accl[4] += hv[j]*b.x; accl[5] += hv[j]*b.y; accl[6] += hv[j]*b.z; accl[7] += hv[j]*b.w;
    const float4 cc = *(const float4*)(w_rn + k*8);
    const float4 d = *(const float4*)(w_rn + k*8 + 4);
    accn[0] += hv[j]*cc.x; accn[1] += hv[j]*cc.y; accn[2] += hv[j]*cc.z; accn[3] += hv[j]*cc.w;
    accn[4] += hv[j]*d.x; accn[5] += hv[j]*d.y; accn[6] += hv[j]*d.z; accn[7] += hv[j]*d.w;
  }
#pragma unroll
  for (int e = 0; e < 8; ++e){ accl[e] = waveRedSum(accl[e]); accn[e] = waveRedSum(accn[e]); }
  if (lane == 0){
#pragma unroll
    for (int e = 0; e < 8; ++e){ red2[w][e] = accl[e]; red2[w][8+e] = accn[e]; }
  }
  __syncthreads();
  if (tid == 0){
    float nv[8];
#pragma unroll
    for (int e = 0; e < 8; ++e){
      const float lr = red2[0][e]+red2[1][e]+red2[2][e]+red2[3][e] + b_rl[e];
      const float lnv = red2[0][8+e]+red2[1][8+e]+red2[2][8+e]+red2[3][8+e] + b_rn[e];
      const float sp = fmaxf(lnv, 0.f) + log1pf(expf(-fabsf(lnv)));
      nv[e] = lr + noise[row*8 + e] * sp;
    }
    int bi = 0; float bvv = nv[0];
#pragma unroll
    for (int e = 1; e < 8; ++e) if (nv[e] > bvv){ bvv = nv[e]; bi = e; }
    int si = (bi == 0) ? 1 : 0;
    float sv = nv[si];
#pragma unroll
    for (int e = 0; e < 8; ++e) if (e != bi && nv[e] > sv){ sv = nv[e]; si = e; }
    const float tt = expf(sv - bvv);
    tok_e[row] = make_int2(bi, si);
    tok_g[row] = make_float2(1.f/(1.f + tt), tt/(1.f + tt));
    slot_of[row*2]     = -1;
    slot_of[row*2 + 1] = -1;
  }
}

__global__ __launch_bounds__(256) void k_assign(const int2* __restrict__ tok_e,
    int* __restrict__ expert_tok, int* __restrict__ slot_of)
{
  const int e = blockIdx.x, tid = threadIdx.x;
  __shared__ int cnt[256];
  expert_tok[e*CAPN + tid] = 0;
  expert_tok[e*CAPN + 256 + tid] = 0;
  int which[8]; int c = 0;
  const int t0 = tid * 8;
#pragma unroll
  for (int j = 0; j < 8; ++j){
    const int2 te = tok_e[t0 + j];
    int wj = -1;
    if (te.x == e) wj = 0; else if (te.y == e) wj = 1;
    which[j] = wj;
    c += (wj >= 0) ? 1 : 0;
  }
  cnt[tid] = c;
  __syncthreads();
  if (tid == 0){
    int run = 0;
    for (int i = 0; i < 256; ++i){ const int v = cnt[i]; cnt[i] = run; run += v; }
  }
  __syncthreads();
  int pos = cnt[tid];
#pragma unroll
  for (int j = 0; j < 8; ++j){
    if (which[j] >= 0){
      if (pos < CAPN){
        expert_tok[e*CAPN + pos] = t0 + j;
        slot_of[(t0 + j)*2 + which[j]] = e*CAPN + pos;
      }
      ++pos;
    }
  }
}

// ffn1: 1024 blocks, XCD-chunked: each XCD owns one expert; mt innermost.
__global__ __launch_bounds__(256) void k_ffn1(const u16* __restrict__ h2b,
    const u16* __restrict__ w1T, const float* __restrict__ b1,
    const int* __restrict__ expert_tok, u16* __restrict__ act)
{
  GEMM_PRE4
  const int id = blockIdx.x;
  const int chunk = (id & 7) * 128 + (id >> 3);
  const int mt = chunk & 3, pcol = (chunk >> 2) & 31, z = chunk >> 7;
  const int row0 = mt*128, col0 = pcol*128;
  gemm_core5<true>(h2b, DD, expert_tok + z*CAPN, w1T + (long)z*DD*DFF, DFF, DD, 0,
                   row0, col0, As0, Bs0, As1, Bs1, acc);
  GEMM_EPI4_VARS
#pragma unroll
  for (int mi = 0; mi < 2; ++mi)
#pragma unroll
    for (int ni = 0; ni < 2; ++ni)
#pragma unroll
      for (int r = 0; r < 16; ++r){
        const int rr = ROW4(mi, r);
        const int cc = COL4(ni);
        const float val = fmaxf(acc[mi][ni][r] + b1[z*DFF + cc], 0.f);
        act[((long)z*CAPN + rr)*DFF + cc] = f2bf(val);
      }
}

// ffn2: split-K=2, 512 blocks, XCD-chunked (expert per XCD); bf16 partials.
__global__ __launch_bounds__(256) void k_ffn2(const u16* __restrict__ act,
    const u16* __restrict__ w2T, u16* __restrict__ partial)
{
  GEMM_PRE4
  const int id = blockIdx.x;
  const int chunk = (id & 7) * 64 + (id >> 3);
  const int ks = chunk & 1, mt = (chunk >> 1) & 3, pcol = (chunk >> 3) & 7, z = chunk >> 6;
  const int row0 = mt*128, col0 = pcol*128;
  gemm_core5<false>(act + (long)z*CAPN*DFF, DFF, nullptr,
                    w2T + (long)z*DFF*DD, DD, 2048, ks*2048,
                    row0, col0, As0, Bs0, As1, Bs1, acc);
  GEMM_EPI4_VARS
  u16* pp = partial + (long)ks*NEXPERT*CAPN*DD;
#pragma unroll
  for (int mi = 0; mi < 2; ++mi)
#pragma unroll
    for (int ni = 0; ni < 2; ++ni)
#pragma unroll
      for (int r = 0; r < 16; ++r){
        const int rr = ROW4(mi, r);
        const int cc = COL4(ni);
        pp[((long)z*CAPN + rr)*DD + cc] = f2bf(acc[mi][ni][r]);
      }
}

// reduce bf16 split-K partials + bias + gate + residual add
__global__ __launch_bounds__(256) void k_combine(float* __restrict__ out,
    const int* __restrict__ slot_of, const float2* __restrict__ tok_g,
    const u16* __restrict__ partial, const float* __restrict__ b2)
{
  const int tok = blockIdx.x, c = threadIdx.x * 4;
  float4 o = *(float4*)(out + (long)tok*DD + c);
  const int2 ss = *(const int2*)(slot_of + tok*2);
  const float2 g = tok_g[tok];
#pragma unroll
  for (int j = 0; j < 2; ++j){
    const int s = j ? ss.y : ss.x;
    const float gw = j ? g.y : g.x;
    if (s >= 0){
      const int e = s >> 9;
      float4 a = *(const float4*)(b2 + e*DD + c);
#pragma unroll
      for (int ks = 0; ks < 2; ++ks){
        const short4v pv = *(const short4v*)(partial + (long)ks*NEXPERT*CAPN*DD + (long)s*DD + c);
        a.x += bf2f((u16)pv[0]); a.y += bf2f((u16)pv[1]);
        a.z += bf2f((u16)pv[2]); a.w += bf2f((u16)pv[3]);
      }
      o.x += gw*a.x; o.y += gw*a.y; o.z += gw*a.z; o.w += gw*a.w;
    }
  }
  *(float4*)(out + (long)tok*DD + c) = o;
}

// ---------------------------------------------------------------- launcher
extern "C" void kernel_launch(void* const* d_in, const int* in_sizes, int n_in,
                              void* d_out, int out_size, void* d_ws, size_t ws_size,
                              hipStream_t stream)
{
  (void)in_sizes; (void)n_in; (void)out_size; (void)ws_size;
  const float* x      = (const float*)d_in[0];
  const float* noise  = (const float*)d_in[1];
  const float* ln1_g  = (const float*)d_in[2];
  const float* ln1_b  = (const float*)d_in[3];
  const float* ln2_g  = (const float*)d_in[4];
  const float* ln2_b  = (const float*)d_in[5];
  const float* w_qkv  = (const float*)d_in[6];
  const float* w_proj = (const float*)d_in[7];
  const float* w_rl   = (const float*)d_in[8];
  const float* b_rl   = (const float*)d_in[9];
  const float* w_rn   = (const float*)d_in[10];
  const float* b_rn   = (const float*)d_in[11];
  const float* w1     = (const float*)d_in[12];
  const float* b1     = (const float*)d_in[13];
  const float* w2     = (const float*)d_in[14];
  const float* b2     = (const float*)d_in[15];
  float* out = (float*)d_out;

  char* p = (char*)d_ws;
  auto carve = [&](size_t bytes) -> void* {
    void* r = (void*)p;
    p += (bytes + 255) & ~(size_t)255;
    return r;
  };
  const size_t SLOT = (size_t)NTOK*DD*2;   // 4 MiB
  float* sin_t      = (float*)carve((size_t)TB*32*4);
  float* cos_t      = (float*)carve((size_t)TB*32*4);
  char*  region     = (char*)carve(SLOT*8);
  u16*   h1    = (u16*)region;                 // dead after qkv gemm
  u16*   v_row = (u16*)(region + SLOT);        // dead after k_vt
  u16*   q_r   = (u16*)(region + SLOT*4);
  u16*   k_r   = (u16*)(region + SLOT*5);
  u16*   v_t   = (u16*)(region + SLOT*6);
  u16*   ao    = (u16*)(region + SLOT*7);
  u16*   aoc   = (u16*)region;                 // slots 0-1, attn chunks
  float2* mLc  = (float2*)(region + SLOT*2);   // attn chunk stats
  u16*   act   = (u16*)region;                 // full region, MoE phase
  u16*   h2b        = (u16*)  carve((size_t)NTOK*DD*2);
  int2*  tok_e      = (int2*) carve((size_t)NTOK*8);
  float2* tok_g     = (float2*)carve((size_t)NTOK*8);
  int*   slot_of    = (int*)  carve((size_t)NTOK*2*4);
  int*   expert_tok = (int*)  carve((size_t)NEXPERT*CAPN*4);
  u16*   wqkvT      = (u16*)  carve((size_t)DD*3*DD*2);
  u16*   wprojT     = (u16*)  carve((size_t)DD*DD*2);
  u16*   w1T        = (u16*)  carve((size_t)NEXPERT*DD*DFF*2);   // 67MB
  u16*   w2T        = (u16*)  carve((size_t)NEXPERT*DFF*DD*2);   // 67MB
  u16*   partial    = (u16*)w1T;              // aliases w1T (dead after ffn1)

  k_prep   <<<6528, 256, 0, stream>>>(w_qkv, w_proj, w1, w2,
                                      wqkvT, wprojT, w1T, w2T, sin_t, cos_t,
                                      x, ln1_g, ln1_b, h1);
  k_gemm_qkv<<<384, 256, 0, stream>>>(h1, wqkvT, sin_t, cos_t, q_r, k_r, v_row);
  k_vt     <<<dim3(16, 32), 256, 0, stream>>>(v_row, v_t);
  k_attn   <<<dim3(8, 32, 2), 512, 0, stream>>>(q_r, k_r, v_t, aoc, mLc);
  k_attn_comb<<<256, 256, 0, stream>>>(aoc, mLc, ao);
  k_gemm_proj<<<128, 256, 0, stream>>>(ao, wprojT, x, out);
  k_ln2r   <<<NTOK, 256, 0, stream>>>(out, ln2_g, ln2_b, w_rl, b_rl, w_rn, b_rn,
                                      noise, h2b, tok_e, tok_g, slot_of);
  k_assign <<<NEXPERT, 256, 0, stream>>>(tok_e, expert_tok, slot_of);
  k_ffn1   <<<1024, 256, 0, stream>>>(h2b, w1T, b1, expert_tok, act);
  k_ffn2   <<<512, 256, 0, stream>>>(act, w2T, partial);
  k_combine<<<NTOK, 256, 0, stream>>>(out, slot_of, tok_g, partial, b2);
}

// Round 19
// 270.772 us; speedup vs baseline: 1.1549x; 1.0139x over previous
//
#include <hip/hip_runtime.h>

// MoE transformer block: prep(sincos+weight transposes+LN1, NT loads) ->
// QKV(+RoPE, +fused V-transpose epilogue) -> split-KV causal flash attn ->
// proj+res -> LN2+router -> assign -> expert FFN (bf16 partials) -> combine.
// Weights K-BLOCKED [K/64][N][64]; prep tile 64k x 256n, NT fp32 loads.
// GEMMs: bf16 MFMA 32x32x16, 128^2 tile, BK=64, global_load_lds dwordx4,
// T2 XOR-swizzle, 2-phase double-buffered pipeline with counted vmcnt.

#define TB 1024   // T
#define DD 1024   // D
#define NTOK 2048 // B*T
#define NEXPERT 8
#define CAPN 512
#define DFF 4096

typedef __attribute__((ext_vector_type(4))) float f32x4;
typedef __attribute__((ext_vector_type(16))) float f32x16;
typedef __attribute__((ext_vector_type(8))) short short8;
typedef __attribute__((ext_vector_type(4))) short short4v;
typedef unsigned short u16;
typedef unsigned int u32;

__device__ __forceinline__ u16 f2bf(float f){
  union { float f; u32 u; } v; v.f = f;
  u32 u = v.u;
  u32 r = (u + 0x7fffu + ((u >> 16) & 1u)) >> 16;
  return (u16)r;
}
__device__ __forceinline__ float bf2f(u16 b){
  union { u32 u; float f; } v; v.u = ((u32)b) << 16;
  return v.f;
}
__device__ __forceinline__ float waveRedSum(float v){
#pragma unroll
  for (int o = 1; o < 64; o <<= 1) v += __shfl_xor(v, o);
  return v;
}

// async global->LDS, 16B per lane, wave-uniform LDS base + lane*16
__device__ __forceinline__ void gl16(const u16* g, u16* l){
  __builtin_amdgcn_global_load_lds(
    (const __attribute__((address_space(1))) u32*)g,
    (__attribute__((address_space(3))) u32*)l, 16, 0, 0);
}

// ------------------------------------------------------------- prep kernel
// Sections: sincos 128 | qkv 192 | proj 64 | w1 2048 | w2 2048 | LN1 2048
// -> grid 6528. Transpose tile = 64k x 256n; dst k-blocked [K/64][N][64].
// fp32 weight reads are non-temporal (streamed once, never reused).
__global__ __launch_bounds__(256) void k_prep(
    const float* __restrict__ w_qkv, const float* __restrict__ w_proj,
    const float* __restrict__ w1, const float* __restrict__ w2,
    u16* __restrict__ wqkvT, u16* __restrict__ wprojT,
    u16* __restrict__ w1T, u16* __restrict__ w2T,
    float* __restrict__ st, float* __restrict__ ct,
    const float* __restrict__ x, const float* __restrict__ ln1_g,
    const float* __restrict__ ln1_b, u16* __restrict__ h1)
{
  const int tid = threadIdx.x;
  int bid = blockIdx.x;
  if (bid < 128){
    const int idx = bid * 256 + tid;
    const int t = idx >> 5, i = idx & 31;
    const float inv = expf((float)(2 * i) * (-0.14391157f));
    const float ang = (float)t * inv;
    st[idx] = sinf(ang);
    ct[idx] = cosf(ang);
    return;
  }
  bid -= 128;
  if (bid >= 4352){
    // LN1 section: one block per token row
    const int row = bid - 4352;
    const int w = tid >> 6, lane = tid & 63;
    const float4 xv = *(const float4*)(x + (long)row*DD + tid*4);
    __shared__ float red[8];
    float s = xv.x + xv.y + xv.z + xv.w;
    s = waveRedSum(s);
    if (lane == 0) red[w] = s;
    __syncthreads();
    const float mean = (red[0]+red[1]+red[2]+red[3]) * (1.f/1024.f);
    const float d0 = xv.x-mean, d1 = xv.y-mean, d2 = xv.z-mean, d3 = xv.w-mean;
    float vs = d0*d0 + d1*d1 + d2*d2 + d3*d3;
    vs = waveRedSum(vs);
    if (lane == 0) red[4+w] = vs;
    __syncthreads();
    const float var = (red[4]+red[5]+red[6]+red[7]) * (1.f/1024.f);
    const float inv = rsqrtf(var + 1e-5f);
    const int c = tid*4;
    short4v p;
    p[0] = (short)f2bf(d0*inv*ln1_g[c+0] + ln1_b[c+0]);
    p[1] = (short)f2bf(d1*inv*ln1_g[c+1] + ln1_b[c+1]);
    p[2] = (short)f2bf(d2*inv*ln1_g[c+2] + ln1_b[c+2]);
    p[3] = (short)f2bf(d3*inv*ln1_g[c+3] + ln1_b[c+3]);
    *(short4v*)(h1 + (long)row*DD + c) = p;
    return;
  }
  const float* src; u16* dst; int N, nnx, tile;
  long zoff = 0;
  if (bid < 192){
    src = w_qkv; dst = wqkvT; N = 3*DD; nnx = 12; tile = bid;
  } else if (bid < 256){
    src = w_proj; dst = wprojT; N = DD; nnx = 4; tile = bid - 192;
  } else if (bid < 2304){
    const int b2 = bid - 256;
    src = w1; dst = w1T; N = DFF; nnx = 16; tile = b2 & 255;
    zoff = (long)(b2 >> 8) * DD * DFF;
  } else {
    const int b2 = bid - 2304;
    src = w2; dst = w2T; N = DD; nnx = 4; tile = b2 & 255;
    zoff = (long)(b2 >> 8) * DFF * DD;
  }
  const int n0 = (tile % nnx) * 256, k0 = (tile / nnx) * 64;

  __shared__ u16 tb[64*258];   // [k][n] bf16, row pitch 258
#pragma unroll
  for (int i = 0; i < 16; ++i){
    const int r = i*4 + (tid >> 6);
    const int c = (tid & 63) * 4;
    const f32x4 v = __builtin_nontemporal_load(
        (const f32x4*)(src + zoff + (long)(k0 + r)*N + n0 + c));
    const u32 lo = (u32)f2bf(v[0]) | ((u32)f2bf(v[1]) << 16);
    const u32 hi = (u32)f2bf(v[2]) | ((u32)f2bf(v[3]) << 16);
    *(u32*)(tb + r*258 + c)     = lo;
    *(u32*)(tb + r*258 + c + 2) = hi;
  }
  __syncthreads();
  const int koct = tid & 7;
  u16* dpb = dst + zoff + (long)k0*N + (long)n0*64 + koct*8;
#pragma unroll
  for (int q = 0; q < 8; ++q){
    const int n = q*32 + (tid >> 3);
    short8 o;
#pragma unroll
    for (int j = 0; j < 8; ++j)
      o[j] = (short)tb[(koct*8 + j)*258 + n];
    *(short8*)(dpb + (long)n*64) = o;
  }
}

// ---------------------------------------------------------------- GEMM core
// C 128x128 tile, 4 waves 2x2, A bf16 [M,K] (opt row-gather),
// B bf16 k-blocked [K/64][BN][64]. BK=64, double-buffered, counted vmcnt,
// T2 XOR-swizzle.
template<bool GATHER>
__device__ __forceinline__ void gemm_core5(
    const u16* __restrict__ A, int lda, const int* __restrict__ rowlist,
    const u16* __restrict__ Bt, int BN, int K, int kstart, int row0, int col0,
    u16* As0, u16* Bs0, u16* As1, u16* Bs1, f32x16 acc[2][2])
{
  const int tid = threadIdx.x;
  const int lane = tid & 63;
  const int w = tid >> 6;
  const int wr = w >> 1, wc = w & 1;
  const int l31 = lane & 31, l5 = lane >> 5;
  const int rr8 = lane >> 3;
  const int cc8 = ((lane & 7) ^ rr8) * 8;

  const u16* Aq[4];
  const u16* Bq[4];
  int coff[4];
#pragma unroll
  for (int j2 = 0; j2 < 4; ++j2){
    const int j = w + 4*j2;
    long ar;
    if constexpr (GATHER) ar = rowlist[row0 + j*8 + rr8];
    else                  ar = row0 + j*8 + rr8;
    Aq[j2] = A + ar*(long)lda + kstart + cc8;
    Bq[j2] = Bt + (long)kstart*BN + (long)(col0 + j*8 + rr8)*64 + cc8;
    coff[j2] = j*512;
  }

  const int swz = (l31 & 7) * 8;

#define STAGE5(AS, BS, KOFF) \
  _Pragma("unroll") \
  for (int j2 = 0; j2 < 4; ++j2){ \
    gl16(Aq[j2] + (KOFF), (AS) + coff[j2]); \
    gl16(Bq[j2] + (long)(KOFF)*BN, (BS) + coff[j2]); \
  }

#define COMPUTE5(AS, BS) \
  _Pragma("unroll") \
  for (int s = 0; s < 4; ++s){ \
    short8 aF[2], bF[2]; \
    const int cread = ((s*16 + l5*8) ^ swz); \
    _Pragma("unroll") \
    for (int mi = 0; mi < 2; ++mi) \
      aF[mi] = *(const short8*)((AS) + (wr*64 + mi*32 + l31)*64 + cread); \
    _Pragma("unroll") \
    for (int ni = 0; ni < 2; ++ni) \
      bF[ni] = *(const short8*)((BS) + (wc*64 + ni*32 + l31)*64 + cread); \
    _Pragma("unroll") \
    for (int mi = 0; mi < 2; ++mi) \
      _Pragma("unroll") \
      for (int ni = 0; ni < 2; ++ni) \
        acc[mi][ni] = __builtin_amdgcn_mfma_f32_32x32x16_bf16(aF[mi], bF[ni], acc[mi][ni], 0, 0, 0); \
  }

  STAGE5(As0, Bs0, 0)

  for (int k0 = 0; k0 < K; k0 += 128){
    STAGE5(As1, Bs1, k0 + 64)
    asm volatile("s_waitcnt vmcnt(8)" ::: "memory");
    __builtin_amdgcn_s_barrier();
    __builtin_amdgcn_sched_barrier(0);
    COMPUTE5(As0, Bs0)
    __builtin_amdgcn_s_barrier();
    if (k0 + 128 < K){
      STAGE5(As0, Bs0, k0 + 128)
      asm volatile("s_waitcnt vmcnt(8)" ::: "memory");
    } else {
      asm volatile("s_waitcnt vmcnt(0)" ::: "memory");
    }
    __builtin_amdgcn_s_barrier();
    __builtin_amdgcn_sched_barrier(0);
    COMPUTE5(As1, Bs1)
    __builtin_amdgcn_s_barrier();
  }
#undef STAGE5
#undef COMPUTE5
}

#define GEMM_PRE4 \
  __shared__ u16 As0[128*64], Bs0[128*64], As1[128*64], Bs1[128*64]; \
  f32x16 acc[2][2]; \
  _Pragma("unroll") for (int i = 0; i < 2; ++i) \
  _Pragma("unroll") for (int j = 0; j < 2; ++j) \
  _Pragma("unroll") for (int q = 0; q < 16; ++q) acc[i][j][q] = 0.f;

#define GEMM_EPI4_VARS \
  const int lane = threadIdx.x & 63; \
  const int wv = threadIdx.x >> 6;   \
  const int wr = wv >> 1, wc = wv & 1; \
  const int l31 = lane & 31, l5 = lane >> 5;

#define ROW4(mi, r) (row0 + wr*64 + (mi)*32 + ((r)&3) + (((r)>>2)<<3) + l5*4)
#define COL4(ni)    (col0 + wc*64 + (ni)*32 + l31)

// ---------------------------------------------------------------- kernels
// QKV GEMM with fused RoPE epilogue (pcol 0-15) and fused V-transpose
// epilogue (pcol 16-23: C tile staged into dead GEMM LDS, re-read
// transposed, written straight to v_t[bh][dh][t]).
__global__ __launch_bounds__(256) void k_gemm_qkv(const u16* __restrict__ h1,
    const u16* __restrict__ wqT, const float* __restrict__ st,
    const float* __restrict__ ct, u16* __restrict__ q_r, u16* __restrict__ k_r,
    u16* __restrict__ v_t)
{
  __shared__ __align__(16) u16 smem[32768];   // 64 KB
  u16* As0 = smem;
  u16* Bs0 = smem + 8192;
  u16* As1 = smem + 16384;
  u16* Bs1 = smem + 24576;
  f32x16 acc[2][2];
#pragma unroll
  for (int i = 0; i < 2; ++i)
#pragma unroll
    for (int j = 0; j < 2; ++j)
#pragma unroll
      for (int q = 0; q < 16; ++q) acc[i][j][q] = 0.f;
  const int id = blockIdx.x;
  const int tid = threadIdx.x;
  const int pcol = id % 24, mt = id / 24;
  const int row0 = mt*128, col0 = pcol*128;
  gemm_core5<false>(h1, DD, nullptr, wqT, 3*DD, DD, 0, row0, col0, As0, Bs0, As1, Bs1, acc);
  GEMM_EPI4_VARS
  if (pcol < 16){
    const int isk = pcol >> 3;
    const int h = (pcol & 7)*2 + wc;
    u16* dstbase = isk ? k_r : q_r;
    const float qs = isk ? 1.f : 0.125f;
#pragma unroll
    for (int mi = 0; mi < 2; ++mi)
#pragma unroll
      for (int r = 0; r < 16; ++r){
        const int rr = ROW4(mi, r);
        const int b = rr >> 10, t = rr & (TB-1);
        const float sv = st[t*32 + l31], cv = ct[t*32 + l31];
        const float a0 = acc[mi][0][r], a1 = acc[mi][1][r];
        const float o1 = (a0*cv - a1*sv) * qs;
        const float o2 = (a1*cv + a0*sv) * qs;
        u16* dst = dstbase + ((long)(b*16 + h)*TB + t)*64 + l31;
        dst[0]  = f2bf(o1);
        dst[32] = f2bf(o2);
      }
  } else {
    // V path: stage tile [t 128][dh 128] into LDS (pitch 129), transpose out.
    u16* vt2 = smem;   // 128*129*2 = 33 KB, all GEMM LDS reads already done
#pragma unroll
    for (int mi = 0; mi < 2; ++mi)
#pragma unroll
      for (int ni = 0; ni < 2; ++ni)
#pragma unroll
        for (int r = 0; r < 16; ++r){
          const int tl = wr*64 + mi*32 + ((r&3) + ((r>>2)<<3) + l5*4);
          const int dl = wc*64 + ni*32 + l31;
          vt2[tl*129 + dl] = f2bf(acc[mi][ni][r]);
        }
    __syncthreads();
    const int dhL = tid & 127;        // 0..127 within tile
    const int thalf = tid >> 7;       // 0/1 -> t-range 64 each
    const int b = row0 >> 10;
    const int t0 = row0 & (TB-1);
    const int h = (pcol - 16)*2 + (dhL >> 6);
    const int dh_in = dhL & 63;
    u16* vp = v_t + ((long)(b*16 + h)*64 + dh_in)*TB + t0 + thalf*64;
#pragma unroll
    for (int q = 0; q < 8; ++q){
      short8 o;
#pragma unroll
      for (int jj = 0; jj < 8; ++jj)
        o[jj] = (short)vt2[(thalf*64 + q*8 + jj)*129 + dhL];
      *(short8*)(vp + q*8) = o;
    }
  }
}

// split-KV flash attention: grid (qtile 8, bh 32, chunk 2), 8 waves.
__global__ __launch_bounds__(512) void k_attn(const u16* __restrict__ q_r,
    const u16* __restrict__ k_r, const u16* __restrict__ v_t,
    u16* __restrict__ aoc, float2* __restrict__ mLc)
{
  const int qt = blockIdx.x, bh = blockIdx.y, ch = blockIdx.z;
  const int kvlen = (qt + 1) * 128;
  const int s_begin = ch * 512;
  if (s_begin >= kvlen) return;
  const int ntile = (min(s_begin + 512, kvlen) - s_begin) >> 6;

  __shared__ u16 K_lds[2][64*64];
  __shared__ u16 V_lds[2][64*64];
  __shared__ u16 P_lds[8][16*80];

  const int tid = threadIdx.x;
  const int w = tid >> 6, lane = tid & 63;
  const int l15 = lane & 15, l4 = lane >> 4;
  const int q0 = qt*128 + w*16;
  u16* P = &P_lds[w][0];

  const int srow = tid >> 3, sslot = tid & 7;
  const u16* kq = k_r + ((long)bh*TB + s_begin + srow)*64 + ((sslot ^ (srow & 7))*8);
  const u16* vq = v_t + ((long)bh*64 + srow)*TB + s_begin + ((sslot ^ (srow & 7))*8);
  u16* kD = &K_lds[0][0] + tid*8;
  u16* vD = &V_lds[0][0] + tid*8;

  const long qoff = ((long)bh*TB + q0 + l15)*64 + l4*8;
  const short8 Qf0 = *(const short8*)(q_r + qoff);
  const short8 Qf1 = *(const short8*)(q_r + qoff + 32);
  const f32x4 fz = {0.f,0.f,0.f,0.f};
  f32x4 O[4];
  float m[4], L[4];
#pragma unroll
  for (int i = 0; i < 4; ++i){ O[i] = fz; m[i] = -1e30f; L[i] = 0.f; }

  gl16(kq, kD);
  gl16(vq, vD);

  for (int t = 0; t < ntile; ++t){
    const int s0 = s_begin + t*64;
    const int cur = t & 1;
    if (t + 1 < ntile){
      gl16(kq + (t+1)*4096, kD + (cur^1)*4096);
      gl16(vq + (t+1)*64,   vD + (cur^1)*4096);
      asm volatile("s_waitcnt vmcnt(2)" ::: "memory");
    } else {
      asm volatile("s_waitcnt vmcnt(0)" ::: "memory");
    }
    __builtin_amdgcn_s_barrier();
    __builtin_amdgcn_sched_barrier(0);
    if (s0 <= q0 + 15){
      const u16* Kb = &K_lds[cur][0];
      const u16* Vb = &V_lds[cur][0];
      f32x4 S[4];
#pragma unroll
      for (int sj = 0; sj < 4; ++sj){
        const int rl = sj*16 + l15;
        const short8 kf0 = *(const short8*)(Kb + rl*64 + ((l4 ^ (rl & 7))*8));
        const short8 kf1 = *(const short8*)(Kb + rl*64 + (((l4 + 4) ^ (rl & 7))*8));
        f32x4 z = fz;
        z = __builtin_amdgcn_mfma_f32_16x16x32_bf16(Qf0, kf0, z, 0, 0, 0);
        z = __builtin_amdgcn_mfma_f32_16x16x32_bf16(Qf1, kf1, z, 0, 0, 0);
        S[sj] = z;
      }
      if (s0 + 63 > q0){
#pragma unroll
        for (int sj = 0; sj < 4; ++sj)
#pragma unroll
          for (int r = 0; r < 4; ++r){
            const int sc = s0 + sj*16 + l15;
            const int qr = q0 + l4*4 + r;
            if (sc > qr) S[sj][r] = -1e30f;
          }
      }
      float vm[4];
#pragma unroll
      for (int r = 0; r < 4; ++r){
        vm[r] = fmaxf(fmaxf(S[0][r], S[1][r]), fmaxf(S[2][r], S[3][r]));
        vm[r] = fmaxf(vm[r], __shfl_xor(vm[r], 1));
        vm[r] = fmaxf(vm[r], __shfl_xor(vm[r], 2));
        vm[r] = fmaxf(vm[r], __shfl_xor(vm[r], 4));
        vm[r] = fmaxf(vm[r], __shfl_xor(vm[r], 8));
      }
      float corr[4], ls[4];
#pragma unroll
      for (int r = 0; r < 4; ++r){
        const float mn = fmaxf(m[r], vm[r]);
        corr[r] = __expf(m[r] - mn);
        m[r] = mn;
        ls[r] = 0.f;
      }
#pragma unroll
      for (int sj = 0; sj < 4; ++sj)
#pragma unroll
        for (int r = 0; r < 4; ++r){
          const float pv = __expf(S[sj][r] - m[r]);
          S[sj][r] = pv;
          ls[r] += pv;
        }
#pragma unroll
      for (int r = 0; r < 4; ++r){
        ls[r] += __shfl_xor(ls[r], 1);
        ls[r] += __shfl_xor(ls[r], 2);
        ls[r] += __shfl_xor(ls[r], 4);
        ls[r] += __shfl_xor(ls[r], 8);
        L[r] = L[r]*corr[r] + ls[r];
      }
#pragma unroll
      for (int nj = 0; nj < 4; ++nj)
#pragma unroll
        for (int r = 0; r < 4; ++r)
          O[nj][r] *= corr[r];
#pragma unroll
      for (int sj = 0; sj < 4; ++sj)
#pragma unroll
        for (int r = 0; r < 4; ++r)
          P[(l4*4 + r)*80 + sj*16 + l15] = f2bf(S[sj][r]);
      asm volatile("s_waitcnt lgkmcnt(0)" ::: "memory");
      __builtin_amdgcn_sched_barrier(0);
      const short8 pf0 = *(const short8*)(P + l15*80 + l4*8);
      const short8 pf1 = *(const short8*)(P + l15*80 + 32 + l4*8);
#pragma unroll
      for (int nj = 0; nj < 4; ++nj){
        const int rl = nj*16 + l15;
        const short8 vf0 = *(const short8*)(Vb + rl*64 + ((l4 ^ (rl & 7))*8));
        const short8 vf1 = *(const short8*)(Vb + rl*64 + (((l4 + 4) ^ (rl & 7))*8));
        O[nj] = __builtin_amdgcn_mfma_f32_16x16x32_bf16(pf0, vf0, O[nj], 0, 0, 0);
        O[nj] = __builtin_amdgcn_mfma_f32_16x16x32_bf16(pf1, vf1, O[nj], 0, 0, 0);
      }
    }
    __builtin_amdgcn_sched_barrier(0);
    __builtin_amdgcn_s_barrier();
  }
  const long obase = ((long)(bh*8 + qt)*2 + ch) * 8192;
#pragma unroll
  for (int nj = 0; nj < 4; ++nj)
#pragma unroll
    for (int r = 0; r < 4; ++r)
      aoc[obase + (long)(w*16 + l4*4 + r)*64 + nj*16 + l15] = f2bf(O[nj][r]);
  if (l15 == 0){
#pragma unroll
    for (int r = 0; r < 4; ++r)
      mLc[((long)(bh*8 + qt)*2 + ch)*128 + w*16 + l4*4 + r] = make_float2(m[r], L[r]);
  }
}

__global__ __launch_bounds__(256) void k_attn_comb(const u16* __restrict__ aoc,
    const float2* __restrict__ mLc, u16* __restrict__ ao)
{
  const int bq = blockIdx.x;
  const int qt = bq & 7, bh = bq >> 3, b = bh >> 4, h = bh & 15;
  const int nc2 = (qt >= 4);
  const int d = threadIdx.x & 63;
  const int r0 = threadIdx.x >> 6;
  const long base = (long)bq * 2 * 8192;
  const long mbase = (long)bq * 2 * 128;
  for (int rp = 0; rp < 32; ++rp){
    const int r = rp*4 + r0;
    const float2 ml0 = mLc[mbase + r];
    float o, Lg;
    if (nc2){
      const float2 ml1 = mLc[mbase + 128 + r];
      const float mg = fmaxf(ml0.x, ml1.x);
      const float w0 = __expf(ml0.x - mg), w1 = __expf(ml1.x - mg);
      o  = w0 * bf2f(aoc[base + (long)r*64 + d]) + w1 * bf2f(aoc[base + 8192 + (long)r*64 + d]);
      Lg = w0 * ml0.y + w1 * ml1.y;
    } else {
      o  = bf2f(aoc[base + (long)r*64 + d]);
      Lg = ml0.y;
    }
    const int t = qt*128 + r;
    ao[((long)b*TB + t)*DD + h*64 + d] = f2bf(o / Lg);
  }
}

__global__ __launch_bounds__(256) void k_gemm_proj(const u16* __restrict__ ao,
    const u16* __restrict__ wpT, const float* __restrict__ x, float* __restrict__ out)
{
  GEMM_PRE4
  const int id = blockIdx.x;
  const int pcol = id % 8, mt = id / 8;
  const int row0 = mt*128, col0 = pcol*128;
  gemm_core5<false>(ao, DD, nullptr, wpT, DD, DD, 0, row0, col0, As0, Bs0, As1, Bs1, acc);
  GEMM_EPI4_VARS
#pragma unroll
  for (int mi = 0; mi < 2; ++mi)
#pragma unroll
    for (int ni = 0; ni < 2; ++ni)
#pragma unroll
      for (int r = 0; r < 16; ++r){
        const int rr = ROW4(mi, r);
        const int cc = COL4(ni);
        out[(long)rr*DD + cc] = x[(long)rr*DD + cc] + acc[mi][ni][r];
      }
}

// fused LN2 + noisy top-2 router; also inits slot_of to -1.
__global__ __launch_bounds__(256) void k_ln2r(const float* __restrict__ x,
    const float* __restrict__ g, const float* __restrict__ bb,
    const float* __restrict__ w_rl, const float* __restrict__ b_rl,
    const float* __restrict__ w_rn, const float* __restrict__ b_rn,
    const float* __restrict__ noise, u16* __restrict__ h2b,
    int2* __restrict__ tok_e, float2* __restrict__ tok_g, int* __restrict__ slot_of)
{
  const int row = blockIdx.x, tid = threadIdx.x;
  const int w = tid >> 6, lane = tid & 63;
  const float4 xv = *(const float4*)(x + (long)row*DD + tid*4);
  __shared__ float red[8];
  __shared__ float red2[4][16];
  float s = xv.x + xv.y + xv.z + xv.w;
  s = waveRedSum(s);
  if (lane == 0) red[w] = s;
  __syncthreads();
  const float mean = (red[0]+red[1]+red[2]+red[3]) * (1.f/1024.f);
  const float d0 = xv.x-mean, d1 = xv.y-mean, d2 = xv.z-mean, d3 = xv.w-mean;
  float vs = d0*d0 + d1*d1 + d2*d2 + d3*d3;
  vs = waveRedSum(vs);
  if (lane == 0) red[4+w] = vs;
  __syncthreads();
  const float var = (red[4]+red[5]+red[6]+red[7]) * (1.f/1024.f);
  const float inv = rsqrtf(var + 1e-5f);
  const int c = tid*4;
  const float hv[4] = {
    d0*inv*g[c+0] + bb[c+0], d1*inv*g[c+1] + bb[c+1],
    d2*inv*g[c+2] + bb[c+2], d3*inv*g[c+3] + bb[c+3]};
  short4v p;
#pragma unroll
  for (int j = 0; j < 4; ++j) p[j] = (short)f2bf(hv[j]);
  *(short4v*)(h2b + (long)row*DD + c) = p;

  float accl[8] = {0,0,0,0,0,0,0,0};
  float accn[8] = {0,0,0,0,0,0,0,0};
#pragma unroll
  for (int j = 0; j < 4; ++j){
    const int k = c + j;
    const float4 a = *(const float4*)(w_rl + k*8);
    const float4 b = *(const float4*)(w_rl + k*8 + 4);
    accl[0] += hv[j]*a.x; accl[1] += hv[j]*a.y; accl[2] += hv[j]*a.z; accl[3] += hv[j]*a.w;
    accl[4] += hv[j]*b.x; accl[5] += hv[j]*b.y; accl[6] += hv[j]*b.z; accl[7] += hv[j]*b.w;
    const float4 cc = *(const float4*)(w_rn + k*8);
    const float4 d = *(const float4*)(w_rn + k*8 + 4);
    accn[0] += hv[j]*cc.x; accn[1] += hv[j]*cc.y; accn[2] += hv[j]*cc.z; accn[3] += hv[j]*cc.w;
    accn[4] += hv[j]*d.x; accn[5] += hv[j]*d.y; accn[6] += hv[j]*d.z; accn[7] += hv[j]*d.w;
  }
#pragma unroll
  for (int e = 0; e < 8; ++e){ accl[e] = waveRedSum(accl[e]); accn[e] = waveRedSum(accn[e]); }
  if (lane == 0){
#pragma unroll
    for (int e = 0; e < 8; ++e){ red2[w][e] = accl[e]; red2[w][8+e] = accn[e]; }
  }
  __syncthreads();
  if (tid == 0){
    float nv[8];
#pragma unroll
    for (int e = 0; e < 8; ++e){
      const float lr = red2[0][e]+red2[1][e]+red2[2][e]+red2[3][e] + b_rl[e];
      const float lnv = red2[0][8+e]+red2[1][8+e]+red2[2][8+e]+red2[3][8+e] + b_rn[e];
      const float sp = fmaxf(lnv, 0.f) + log1pf(expf(-fabsf(lnv)));
      nv[e] = lr + noise[row*8 + e] * sp;
    }
    int bi = 0; float bvv = nv[0];
#pragma unroll
    for (int e = 1; e < 8; ++e) if (nv[e] > bvv){ bvv = nv[e]; bi = e; }
    int si = (bi == 0) ? 1 : 0;
    float sv = nv[si];
#pragma unroll
    for (int e = 0; e < 8; ++e) if (e != bi && nv[e] > sv){ sv = nv[e]; si = e; }
    const float tt = expf(sv - bvv);
    tok_e[row] = make_int2(bi, si);
    tok_g[row] = make_float2(1.f/(1.f + tt), tt/(1.f + tt));
    slot_of[row*2]     = -1;
    slot_of[row*2 + 1] = -1;
  }
}

__global__ __launch_bounds__(256) void k_assign(const int2* __restrict__ tok_e,
    int* __restrict__ expert_tok, int* __restrict__ slot_of)
{
  const int e = blockIdx.x, tid = threadIdx.x;
  __shared__ int cnt[256];
  expert_tok[e*CAPN + tid] = 0;
  expert_tok[e*CAPN + 256 + tid] = 0;
  int which[8]; int c = 0;
  const int t0 = tid * 8;
#pragma unroll
  for (int j = 0; j < 8; ++j){
    const int2 te = tok_e[t0 + j];
    int wj = -1;
    if (te.x == e) wj = 0; else if (te.y == e) wj = 1;
    which[j] = wj;
    c += (wj >= 0) ? 1 : 0;
  }
  cnt[tid] = c;
  __syncthreads();
  if (tid == 0){
    int run = 0;
    for (int i = 0; i < 256; ++i){ const int v = cnt[i]; cnt[i] = run; run += v; }
  }
  __syncthreads();
  int pos = cnt[tid];
#pragma unroll
  for (int j = 0; j < 8; ++j){
    if (which[j] >= 0){
      if (pos < CAPN){
        expert_tok[e*CAPN + pos] = t0 + j;
        slot_of[(t0 + j)*2 + which[j]] = e*CAPN + pos;
      }
      ++pos;
    }
  }
}

// ffn1: 1024 blocks, XCD-chunked: each XCD owns one expert; mt innermost.
__global__ __launch_bounds__(256) void k_ffn1(const u16* __restrict__ h2b,
    const u16* __restrict__ w1T, const float* __restrict__ b1,
    const int* __restrict__ expert_tok, u16* __restrict__ act)
{
  GEMM_PRE4
  const int id = blockIdx.x;
  const int chunk = (id & 7) * 128 + (id >> 3);
  const int mt = chunk & 3, pcol = (chunk >> 2) & 31, z = chunk >> 7;
  const int row0 = mt*128, col0 = pcol*128;
  gemm_core5<true>(h2b, DD, expert_tok + z*CAPN, w1T + (long)z*DD*DFF, DFF, DD, 0,
                   row0, col0, As0, Bs0, As1, Bs1, acc);
  GEMM_EPI4_VARS
#pragma unroll
  for (int mi = 0; mi < 2; ++mi)
#pragma unroll
    for (int ni = 0; ni < 2; ++ni)
#pragma unroll
      for (int r = 0; r < 16; ++r){
        const int rr = ROW4(mi, r);
        const int cc = COL4(ni);
        const float val = fmaxf(acc[mi][ni][r] + b1[z*DFF + cc], 0.f);
        act[((long)z*CAPN + rr)*DFF + cc] = f2bf(val);
      }
}

// ffn2: split-K=2, 512 blocks, XCD-chunked (expert per XCD); bf16 partials.
__global__ __launch_bounds__(256) void k_ffn2(const u16* __restrict__ act,
    const u16* __restrict__ w2T, u16* __restrict__ partial)
{
  GEMM_PRE4
  const int id = blockIdx.x;
  const int chunk = (id & 7) * 64 + (id >> 3);
  const int ks = chunk & 1, mt = (chunk >> 1) & 3, pcol = (chunk >> 3) & 7, z = chunk >> 6;
  const int row0 = mt*128, col0 = pcol*128;
  gemm_core5<false>(act + (long)z*CAPN*DFF, DFF, nullptr,
                    w2T + (long)z*DFF*DD, DD, 2048, ks*2048,
                    row0, col0, As0, Bs0, As1, Bs1, acc);
  GEMM_EPI4_VARS
  u16* pp = partial + (long)ks*NEXPERT*CAPN*DD;
#pragma unroll
  for (int mi = 0; mi < 2; ++mi)
#pragma unroll
    for (int ni = 0; ni < 2; ++ni)
#pragma unroll
      for (int r = 0; r < 16; ++r){
        const int rr = ROW4(mi, r);
        const int cc = COL4(ni);
        pp[((long)z*CAPN + rr)*DD + cc] = f2bf(acc[mi][ni][r]);
      }
}

// reduce bf16 split-K partials + bias + gate + residual add
__global__ __launch_bounds__(256) void k_combine(float* __restrict__ out,
    const int* __restrict__ slot_of, const float2* __restrict__ tok_g,
    const u16* __restrict__ partial, const float* __restrict__ b2)
{
  const int tok = blockIdx.x, c = threadIdx.x * 4;
  float4 o = *(float4*)(out + (long)tok*DD + c);
  const int2 ss = *(const int2*)(slot_of + tok*2);
  const float2 g = tok_g[tok];
#pragma unroll
  for (int j = 0; j < 2; ++j){
    const int s = j ? ss.y : ss.x;
    const float gw = j ? g.y : g.x;
    if (s >= 0){
      const int e = s >> 9;
      float4 a = *(const float4*)(b2 + e*DD + c);
#pragma unroll
      for (int ks = 0; ks < 2; ++ks){
        const short4v pv = *(const short4v*)(partial + (long)ks*NEXPERT*CAPN*DD + (long)s*DD + c);
        a.x += bf2f((u16)pv[0]); a.y += bf2f((u16)pv[1]);
        a.z += bf2f((u16)pv[2]); a.w += bf2f((u16)pv[3]);
      }
      o.x += gw*a.x; o.y += gw*a.y; o.z += gw*a.z; o.w += gw*a.w;
    }
  }
  *(float4*)(out + (long)tok*DD + c) = o;
}

// ---------------------------------------------------------------- launcher
extern "C" void kernel_launch(void* const* d_in, const int* in_sizes, int n_in,
                              void* d_out, int out_size, void* d_ws, size_t ws_size,
                              hipStream_t stream)
{
  (void)in_sizes; (void)n_in; (void)out_size; (void)ws_size;
  const float* x      = (const float*)d_in[0];
  const float* noise  = (const float*)d_in[1];
  const float* ln1_g  = (const float*)d_in[2];
  const float* ln1_b  = (const float*)d_in[3];
  const float* ln2_g  = (const float*)d_in[4];
  const float* ln2_b  = (const float*)d_in[5];
  const float* w_qkv  = (const float*)d_in[6];
  const float* w_proj = (const float*)d_in[7];
  const float* w_rl   = (const float*)d_in[8];
  const float* b_rl   = (const float*)d_in[9];
  const float* w_rn   = (const float*)d_in[10];
  const float* b_rn   = (const float*)d_in[11];
  const float* w1     = (const float*)d_in[12];
  const float* b1     = (const float*)d_in[13];
  const float* w2     = (const float*)d_in[14];
  const float* b2     = (const float*)d_in[15];
  float* out = (float*)d_out;

  char* p = (char*)d_ws;
  auto carve = [&](size_t bytes) -> void* {
    void* r = (void*)p;
    p += (bytes + 255) & ~(size_t)255;
    return r;
  };
  const size_t SLOT = (size_t)NTOK*DD*2;   // 4 MiB
  float* sin_t      = (float*)carve((size_t)TB*32*4);
  float* cos_t      = (float*)carve((size_t)TB*32*4);
  char*  region     = (char*)carve(SLOT*8);
  u16*   h1    = (u16*)region;                 // dead after qkv gemm
  u16*   q_r   = (u16*)(region + SLOT*4);
  u16*   k_r   = (u16*)(region + SLOT*5);
  u16*   v_t   = (u16*)(region + SLOT*6);
  u16*   ao    = (u16*)(region + SLOT*7);
  u16*   aoc   = (u16*)region;                 // slots 0-1, attn chunks
  float2* mLc  = (float2*)(region + SLOT*2);   // attn chunk stats
  u16*   act   = (u16*)region;                 // full region, MoE phase
  u16*   h2b        = (u16*)  carve((size_t)NTOK*DD*2);
  int2*  tok_e      = (int2*) carve((size_t)NTOK*8);
  float2* tok_g     = (float2*)carve((size_t)NTOK*8);
  int*   slot_of    = (int*)  carve((size_t)NTOK*2*4);
  int*   expert_tok = (int*)  carve((size_t)NEXPERT*CAPN*4);
  u16*   wqkvT      = (u16*)  carve((size_t)DD*3*DD*2);
  u16*   wprojT     = (u16*)  carve((size_t)DD*DD*2);
  u16*   w1T        = (u16*)  carve((size_t)NEXPERT*DD*DFF*2);   // 67MB
  u16*   w2T        = (u16*)  carve((size_t)NEXPERT*DFF*DD*2);   // 67MB
  u16*   partial    = (u16*)w1T;              // aliases w1T (dead after ffn1)

  k_prep   <<<6528, 256, 0, stream>>>(w_qkv, w_proj, w1, w2,
                                      wqkvT, wprojT, w1T, w2T, sin_t, cos_t,
                                      x, ln1_g, ln1_b, h1);
  k_gemm_qkv<<<384, 256, 0, stream>>>(h1, wqkvT, sin_t, cos_t, q_r, k_r, v_t);
  k_attn   <<<dim3(8, 32, 2), 512, 0, stream>>>(q_r, k_r, v_t, aoc, mLc);
  k_attn_comb<<<256, 256, 0, stream>>>(aoc, mLc, ao);
  k_gemm_proj<<<128, 256, 0, stream>>>(ao, wprojT, x, out);
  k_ln2r   <<<NTOK, 256, 0, stream>>>(out, ln2_g, ln2_b, w_rl, b_rl, w_rn, b_rn,
                                      noise, h2b, tok_e, tok_g, slot_of);
  k_assign <<<NEXPERT, 256, 0, stream>>>(tok_e, expert_tok, slot_of);
  k_ffn1   <<<1024, 256, 0, stream>>>(h2b, w1T, b1, expert_tok, act);
  k_ffn2   <<<512, 256, 0, stream>>>(act, w2T, partial);
  k_combine<<<NTOK, 256, 0, stream>>>(out, slot_of, tok_g, partial, b2);
}